// Round 1
// baseline (890.650 us; speedup 1.0000x reference)
//
#include <hip/hip_runtime.h>
#include <hip/hip_bf16.h>
#include <math.h>

#define Bq 4
#define Lq 2048
#define Dq 512
#define Hq 8
#define DKq 64
#define Uq 24
#define TSCAN 128
#define NTILE (Lq / TSCAN)   // 16

// ---------------------------------------------------------------------------
// fp32 GEMM: C[M x 512] = A[M x 512] @ W[512 x 512] + bias[512]
// 128x64 tile, 256 threads, 8x4 microtile.
// ---------------------------------------------------------------------------
#define TBM 128
#define TBN 64
#define TBK 16

__global__ __launch_bounds__(256) void gemm_bias(
    const float* __restrict__ A, const float* __restrict__ W,
    const float* __restrict__ bias, float* __restrict__ C) {
  __shared__ float As[TBK][TBM + 4];  // [k][m], padded to kill read conflicts
  __shared__ float Bs[TBK][TBN];      // [k][n]
  const int K = 512;
  int bm = blockIdx.x;
  int bn = blockIdx.y;
  int tid = threadIdx.x;
  int tx = tid & 15;   // N dir (16 x 4)
  int ty = tid >> 4;   // M dir (16 x 8)

  float acc[8][4] = {};

  for (int k0 = 0; k0 < K; k0 += TBK) {
    // A tile: 128 rows x 16 k = 512 float4 slots; 2 per thread
#pragma unroll
    for (int j = 0; j < 2; ++j) {
      int s = tid * 2 + j;
      int row = s >> 2;
      int kq = s & 3;
      float4 a = *reinterpret_cast<const float4*>(
          &A[(size_t)(bm * TBM + row) * K + k0 + kq * 4]);
      As[kq * 4 + 0][row] = a.x;
      As[kq * 4 + 1][row] = a.y;
      As[kq * 4 + 2][row] = a.z;
      As[kq * 4 + 3][row] = a.w;
    }
    // B tile: 16 k x 64 n = 256 float4 slots; 1 per thread
    {
      int krow = tid >> 4;
      int nq = tid & 15;
      float4 b = *reinterpret_cast<const float4*>(
          &W[(size_t)(k0 + krow) * 512 + bn * TBN + nq * 4]);
      *reinterpret_cast<float4*>(&Bs[krow][nq * 4]) = b;
    }
    __syncthreads();
#pragma unroll
    for (int kk = 0; kk < TBK; ++kk) {
      float a[8], b[4];
      *(float4*)&a[0] = *(float4*)&As[kk][ty * 8];
      *(float4*)&a[4] = *(float4*)&As[kk][ty * 8 + 4];
      *(float4*)&b[0] = *(float4*)&Bs[kk][tx * 4];
#pragma unroll
      for (int i = 0; i < 8; ++i)
#pragma unroll
        for (int j = 0; j < 4; ++j) acc[i][j] += a[i] * b[j];
    }
    __syncthreads();
  }
  int col = bn * TBN + tx * 4;
  float4 bv = *reinterpret_cast<const float4*>(&bias[col]);
#pragma unroll
  for (int i = 0; i < 8; ++i) {
    int row = bm * TBM + ty * 8 + i;
    float4 o;
    o.x = acc[i][0] + bv.x;
    o.y = acc[i][1] + bv.y;
    o.z = acc[i][2] + bv.z;
    o.w = acc[i][3] + bv.w;
    *reinterpret_cast<float4*>(&C[(size_t)row * 512 + col]) = o;
  }
}

// ---------------------------------------------------------------------------
// m[b,h,l] = max_s(q[b,l,h,:].k[b,idx[l,s],h,:]) - sum_s(...)/L
// one wave per (b,h,l)
// ---------------------------------------------------------------------------
__global__ __launch_bounds__(256) void compute_m(
    const float* __restrict__ q, const float* __restrict__ k,
    const int* __restrict__ idxs, float* __restrict__ m) {
  int wid = blockIdx.x * 4 + (threadIdx.x >> 6);
  int lane = threadIdx.x & 63;
  int l = wid & (Lq - 1);
  int bh = wid >> 11;
  int h = bh & (Hq - 1);
  int b = bh >> 3;
  float qv = q[((size_t)b * Lq + l) * Dq + h * DKq + lane];
  float mx = -INFINITY, sm = 0.f;
#pragma unroll 4
  for (int s = 0; s < Uq; ++s) {
    int j = idxs[l * Uq + s];
    float kv = k[((size_t)b * Lq + j) * Dq + h * DKq + lane];
    float p = qv * kv;
#pragma unroll
    for (int off = 32; off; off >>= 1) p += __shfl_xor(p, off, 64);
    mx = fmaxf(mx, p);
    sm += p;
  }
  if (lane == 0) m[wid] = mx - sm * (1.0f / Lq);
}

// ---------------------------------------------------------------------------
// top-24 per (b,h): iterative argmax, tie-break smaller index (lax.top_k)
// ---------------------------------------------------------------------------
__global__ __launch_bounds__(256) void topk_kernel(
    const float* __restrict__ m, int* __restrict__ mtop) {
  __shared__ float vals[Lq];
  __shared__ float rv[256];
  __shared__ int ri[256];
  int bh = blockIdx.x;
  int tid = threadIdx.x;
  for (int i = tid; i < Lq; i += 256) vals[i] = m[(size_t)bh * Lq + i];
  __syncthreads();
  for (int t = 0; t < Uq; ++t) {
    float best = -INFINITY;
    int bi = Lq;
    for (int i = tid; i < Lq; i += 256) {
      float v = vals[i];
      if (v > best || (v == best && i < bi)) { best = v; bi = i; }
    }
    rv[tid] = best;
    ri[tid] = bi;
    __syncthreads();
    for (int s = 128; s; s >>= 1) {
      if (tid < s) {
        float ov = rv[tid + s];
        int oi = ri[tid + s];
        if (ov > rv[tid] || (ov == rv[tid] && oi < ri[tid])) {
          rv[tid] = ov;
          ri[tid] = oi;
        }
      }
      __syncthreads();
    }
    if (tid == 0) {
      mtop[bh * Uq + t] = ri[0];
      vals[ri[0]] = -INFINITY;
    }
    __syncthreads();
  }
}

// repl[b,h,l] = u if l == mtop[b,h,u] else -1 (table pre-filled with -1)
__global__ void scatter_repl(const int* __restrict__ mtop, int* __restrict__ repl) {
  int t = blockIdx.x * blockDim.x + threadIdx.x;
  if (t < Bq * Hq * Uq) {
    int bh = t / Uq;
    repl[(size_t)bh * Lq + mtop[t]] = t % Uq;
  }
}

// ---------------------------------------------------------------------------
// attention row per (b,h,u): causal scores + softmax + P@V
// ---------------------------------------------------------------------------
__global__ __launch_bounds__(256) void attn_kernel(
    const float* __restrict__ q, const float* __restrict__ k,
    const float* __restrict__ v, const int* __restrict__ mtop,
    float* __restrict__ attnv) {
  __shared__ float sc[Lq];  // scores -> exp(scores - max)
  __shared__ float red[4 * DKq];
  __shared__ float rmax[4], rsum[4];
  int blk = blockIdx.x;  // (b*H+h)*U + u
  int bh = blk / Uq;
  int h = bh & (Hq - 1);
  int b = bh >> 3;
  int tid = threadIdx.x;
  int wave = tid >> 6;
  int lane = tid & 63;
  int i0 = mtop[blk];
  int n = i0 + 1;  // causal: j <= i0 allowed
  float qv = q[((size_t)b * Lq + i0) * Dq + h * DKq + lane];
  const float scale = 0.044194173824159216f;  // 1/sqrt(512)

  for (int j = wave; j < n; j += 4) {
    float kv = k[((size_t)b * Lq + j) * Dq + h * DKq + lane];
    float p = qv * kv;
#pragma unroll
    for (int off = 32; off; off >>= 1) p += __shfl_xor(p, off, 64);
    if (lane == 0) sc[j] = p * scale;
  }
  __syncthreads();

  float mx = -INFINITY;
  for (int j = tid; j < n; j += 256) mx = fmaxf(mx, sc[j]);
#pragma unroll
  for (int off = 32; off; off >>= 1) mx = fmaxf(mx, __shfl_xor(mx, off, 64));
  if (lane == 0) rmax[wave] = mx;
  __syncthreads();
  mx = fmaxf(fmaxf(rmax[0], rmax[1]), fmaxf(rmax[2], rmax[3]));

  float sm = 0.f;
  for (int j = tid; j < n; j += 256) {
    float e = __expf(sc[j] - mx);
    sc[j] = e;
    sm += e;
  }
#pragma unroll
  for (int off = 32; off; off >>= 1) sm += __shfl_xor(sm, off, 64);
  if (lane == 0) rsum[wave] = sm;
  __syncthreads();
  float inv = 1.0f / (rsum[0] + rsum[1] + rsum[2] + rsum[3]);

  float acc = 0.f;
  for (int j = wave; j < n; j += 4)
    acc += sc[j] * v[((size_t)b * Lq + j) * Dq + h * DKq + lane];
  red[wave * DKq + lane] = acc;
  __syncthreads();
  if (wave == 0) {
    float o = (red[lane] + red[DKq + lane] + red[2 * DKq + lane] +
               red[3 * DKq + lane]) * inv;
    attnv[(size_t)blk * DKq + lane] = o;
  }
}

// ---------------------------------------------------------------------------
// cumsum over L (tiled scan) + scatter of attn values + context build
// ---------------------------------------------------------------------------
__global__ __launch_bounds__(256) void tile_sum(const float* __restrict__ v,
                                                float* __restrict__ tsum) {
  int blk = blockIdx.x;  // B*NTILE
  int tile = blk & (NTILE - 1);
  int b = blk >> 4;
  int tid = threadIdx.x;
  for (int c = 0; c < Dq; c += 256) {
    int d = c + tid;
    float s = 0.f;
    for (int r = 0; r < TSCAN; ++r)
      s += v[((size_t)b * Lq + tile * TSCAN + r) * Dq + d];
    tsum[((size_t)b * NTILE + tile) * Dq + d] = s;
  }
}

__global__ void tile_prefix(float* __restrict__ tsum) {
  int t = blockIdx.x * blockDim.x + threadIdx.x;  // B*D
  if (t >= Bq * Dq) return;
  int b = t / Dq;
  int d = t % Dq;
  float run = 0.f;
  for (int i = 0; i < NTILE; ++i) {
    size_t off = ((size_t)b * NTILE + i) * Dq + d;
    float x = tsum[off];
    tsum[off] = run;
    run += x;
  }
}

__global__ __launch_bounds__(256) void build_context(
    const float* __restrict__ v, const float* __restrict__ tsum,
    const int* __restrict__ repl, const float* __restrict__ attnv,
    float* __restrict__ ctx) {
  int blk = blockIdx.x;  // B*NTILE
  int tile = blk & (NTILE - 1);
  int b = blk >> 4;
  int tid = threadIdx.x;
  for (int c = 0; c < Dq; c += 256) {
    int d = c + tid;
    int h = d >> 6;
    float run = tsum[((size_t)b * NTILE + tile) * Dq + d];
    for (int r = 0; r < TSCAN; ++r) {
      int l = tile * TSCAN + r;
      run += v[((size_t)b * Lq + l) * Dq + d];
      int u = repl[((size_t)(b * Hq + h)) * Lq + l];
      float val = (u >= 0)
                      ? attnv[(((size_t)(b * Hq + h)) * Uq + u) * DKq + (d & 63)]
                      : run;
      ctx[((size_t)b * Lq + l) * Dq + d] = val;
    }
  }
}

// ---------------------------------------------------------------------------
extern "C" void kernel_launch(void* const* d_in, const int* in_sizes, int n_in,
                              void* d_out, int out_size, void* d_ws,
                              size_t ws_size, hipStream_t stream) {
  const float* queries = (const float*)d_in[0];
  const float* keys    = (const float*)d_in[1];
  const float* values  = (const float*)d_in[2];
  const int*   idxs    = (const int*)d_in[3];
  const float* Wq = (const float*)d_in[4];
  const float* bq = (const float*)d_in[5];
  const float* Wk = (const float*)d_in[6];
  const float* bk = (const float*)d_in[7];
  const float* Wv = (const float*)d_in[8];
  const float* bv = (const float*)d_in[9];
  const float* Wo = (const float*)d_in[10];
  const float* bo = (const float*)d_in[11];
  float* out = (float*)d_out;

  const size_t BLD = (size_t)Bq * Lq * Dq;  // 4,194,304
  float* q     = (float*)d_ws;
  float* k     = q + BLD;
  float* v     = k + BLD;
  float* ctx   = v + BLD;
  float* m     = ctx + BLD;                        // B*H*L
  float* attnv = m + (size_t)Bq * Hq * Lq;         // B*H*U*DK
  float* tsum  = attnv + (size_t)Bq * Hq * Uq * DKq;  // B*NTILE*D
  int*   mtop  = (int*)(tsum + (size_t)Bq * NTILE * Dq);  // B*H*U
  int*   repl  = mtop + Bq * Hq * Uq;              // B*H*L

  dim3 ggrid(64, 8);  // M=8192/128, N=512/64

  // projections (fp32 — exact enough that top-k matches reference)
  gemm_bias<<<ggrid, 256, 0, stream>>>(queries, Wq, bq, q);
  gemm_bias<<<ggrid, 256, 0, stream>>>(keys, Wk, bk, k);
  gemm_bias<<<ggrid, 256, 0, stream>>>(values, Wv, bv, v);

  // sparsity metric + top-k
  compute_m<<<(Bq * Hq * Lq) / 4, 256, 0, stream>>>(q, k, idxs, m);
  topk_kernel<<<Bq * Hq, 256, 0, stream>>>(m, mtop);

  hipMemsetAsync(repl, 0xFF, (size_t)Bq * Hq * Lq * sizeof(int), stream);
  scatter_repl<<<3, 256, 0, stream>>>(mtop, repl);

  // attention on the top-24 rows
  attn_kernel<<<Bq * Hq * Uq, 256, 0, stream>>>(q, k, v, mtop, attnv);

  // cumsum context + scatter
  tile_sum<<<Bq * NTILE, 256, 0, stream>>>(v, tsum);
  tile_prefix<<<(Bq * Dq + 255) / 256, 256, 0, stream>>>(tsum);
  build_context<<<Bq * NTILE, 256, 0, stream>>>(v, tsum, repl, attnv, ctx);

  // output projection
  gemm_bias<<<ggrid, 256, 0, stream>>>(ctx, Wo, bo, out);
}

// Round 2
// 601.674 us; speedup vs baseline: 1.4803x; 1.4803x over previous
//
#include <hip/hip_runtime.h>
#include <hip/hip_bf16.h>
#include <math.h>

#define Bq 4
#define Lq 2048
#define Dq 512
#define Hq 8
#define DKq 64
#define Uq 24
#define TSCAN 128
#define NTILE (Lq / TSCAN)   // 16

// ---------------------------------------------------------------------------
// fp32 GEMM: C[M x 512] = A[M x 512] @ W[512 x 512] + bias[512]
// 128x64 tile, 256 threads, 8x4 microtile.
// ---------------------------------------------------------------------------
#define TBM 128
#define TBN 64
#define TBK 16

__global__ __launch_bounds__(256) void gemm_bias(
    const float* __restrict__ A, const float* __restrict__ W,
    const float* __restrict__ bias, float* __restrict__ C) {
  __shared__ float As[TBK][TBM + 4];  // [k][m], padded
  __shared__ float Bs[TBK][TBN];      // [k][n]
  const int K = 512;
  int bm = blockIdx.x;
  int bn = blockIdx.y;
  int tid = threadIdx.x;
  int tx = tid & 15;   // N dir (16 x 4)
  int ty = tid >> 4;   // M dir (16 x 8)

  float acc[8][4] = {};

  for (int k0 = 0; k0 < K; k0 += TBK) {
#pragma unroll
    for (int j = 0; j < 2; ++j) {
      int s = tid * 2 + j;
      int row = s >> 2;
      int kq = s & 3;
      float4 a = *reinterpret_cast<const float4*>(
          &A[(size_t)(bm * TBM + row) * K + k0 + kq * 4]);
      As[kq * 4 + 0][row] = a.x;
      As[kq * 4 + 1][row] = a.y;
      As[kq * 4 + 2][row] = a.z;
      As[kq * 4 + 3][row] = a.w;
    }
    {
      int krow = tid >> 4;
      int nq = tid & 15;
      float4 b = *reinterpret_cast<const float4*>(
          &W[(size_t)(k0 + krow) * 512 + bn * TBN + nq * 4]);
      *reinterpret_cast<float4*>(&Bs[krow][nq * 4]) = b;
    }
    __syncthreads();
#pragma unroll
    for (int kk = 0; kk < TBK; ++kk) {
      float a[8], b[4];
      *(float4*)&a[0] = *(float4*)&As[kk][ty * 8];
      *(float4*)&a[4] = *(float4*)&As[kk][ty * 8 + 4];
      *(float4*)&b[0] = *(float4*)&Bs[kk][tx * 4];
#pragma unroll
      for (int i = 0; i < 8; ++i)
#pragma unroll
        for (int j = 0; j < 4; ++j) acc[i][j] += a[i] * b[j];
    }
    __syncthreads();
  }
  int col = bn * TBN + tx * 4;
  float4 bv = *reinterpret_cast<const float4*>(&bias[col]);
#pragma unroll
  for (int i = 0; i < 8; ++i) {
    int row = bm * TBM + ty * 8 + i;
    float4 o;
    o.x = acc[i][0] + bv.x;
    o.y = acc[i][1] + bv.y;
    o.z = acc[i][2] + bv.z;
    o.w = acc[i][3] + bv.w;
    *reinterpret_cast<float4*>(&C[(size_t)row * 512 + col]) = o;
  }
}

// ---------------------------------------------------------------------------
// m[b,h,l] = max_s(q.k_sample) - sum_s(q.k_sample)/L   (one wave per (b,h,l))
// ---------------------------------------------------------------------------
__global__ __launch_bounds__(256) void compute_m(
    const float* __restrict__ q, const float* __restrict__ k,
    const int* __restrict__ idxs, float* __restrict__ m) {
  int wid = blockIdx.x * 4 + (threadIdx.x >> 6);
  int lane = threadIdx.x & 63;
  int l = wid & (Lq - 1);
  int bh = wid >> 11;
  int h = bh & (Hq - 1);
  int b = bh >> 3;
  float qv = q[((size_t)b * Lq + l) * Dq + h * DKq + lane];
  float mx = -INFINITY, sm = 0.f;
#pragma unroll 4
  for (int s = 0; s < Uq; ++s) {
    int j = idxs[l * Uq + s];
    float kv = k[((size_t)b * Lq + j) * Dq + h * DKq + lane];
    float p = qv * kv;
#pragma unroll
    for (int off = 32; off; off >>= 1) p += __shfl_xor(p, off, 64);
    mx = fmaxf(mx, p);
    sm += p;
  }
  if (lane == 0) m[wid] = mx - sm * (1.0f / Lq);
}

// ---------------------------------------------------------------------------
// top-24 per (b,h): iterative argmax, tie-break smaller index (lax.top_k)
// ---------------------------------------------------------------------------
__global__ __launch_bounds__(256) void topk_kernel(
    const float* __restrict__ m, int* __restrict__ mtop) {
  __shared__ float vals[Lq];
  __shared__ float rv[256];
  __shared__ int ri[256];
  int bh = blockIdx.x;
  int tid = threadIdx.x;
  for (int i = tid; i < Lq; i += 256) vals[i] = m[(size_t)bh * Lq + i];
  __syncthreads();
  for (int t = 0; t < Uq; ++t) {
    float best = -INFINITY;
    int bi = Lq;
    for (int i = tid; i < Lq; i += 256) {
      float v = vals[i];
      if (v > best || (v == best && i < bi)) { best = v; bi = i; }
    }
    rv[tid] = best;
    ri[tid] = bi;
    __syncthreads();
    for (int s = 128; s; s >>= 1) {
      if (tid < s) {
        float ov = rv[tid + s];
        int oi = ri[tid + s];
        if (ov > rv[tid] || (ov == rv[tid] && oi < ri[tid])) {
          rv[tid] = ov;
          ri[tid] = oi;
        }
      }
      __syncthreads();
    }
    if (tid == 0) {
      mtop[bh * Uq + t] = ri[0];
      vals[ri[0]] = -INFINITY;
    }
    __syncthreads();
  }
}

// repl[b,h,l] = u if l == mtop[b,h,u] else -1 (table pre-filled with -1)
__global__ void scatter_repl(const int* __restrict__ mtop, int* __restrict__ repl) {
  int t = blockIdx.x * blockDim.x + threadIdx.x;
  if (t < Bq * Hq * Uq) {
    int bh = t / Uq;
    repl[(size_t)bh * Lq + mtop[t]] = t % Uq;
  }
}

// ---------------------------------------------------------------------------
// scores[bh][u][j] = (q[b,i0[u],h,:] . k[b,j,h,:]) / sqrt(D)
// grid: (8 j-tiles of 256, 32 bh). LDS-staged, register-tiled 3u x 2j.
// ---------------------------------------------------------------------------
#define JT 256
#define JS 64

__global__ __launch_bounds__(256) void scores_kernel(
    const float* __restrict__ q, const float* __restrict__ k,
    const int* __restrict__ mtop, float* __restrict__ scg) {
  __shared__ float qs[Uq][DKq + 1];   // 24 x 65 (pad: spread banks)
  __shared__ float ks[JS][DKq + 1];   // 64 x 65
  __shared__ int i0s[Uq];
  int bh = blockIdx.y;
  int jt = blockIdx.x;
  int h = bh & (Hq - 1);
  int b = bh >> 3;
  int tid = threadIdx.x;
  if (tid < Uq) i0s[tid] = mtop[bh * Uq + tid];
  __syncthreads();
  for (int s = tid; s < Uq * 16; s += 256) {
    int u = s >> 4, qd = (s & 15) * 4;
    float4 t = *(const float4*)&q[((size_t)b * Lq + i0s[u]) * Dq + h * DKq + qd];
    qs[u][qd] = t.x; qs[u][qd + 1] = t.y; qs[u][qd + 2] = t.z; qs[u][qd + 3] = t.w;
  }
  int jp = tid & 31;   // j pair -> j0=2*jp, j1=2*jp+1
  int ug = tid >> 5;   // 0..7, each owns 3 u's
  const float scale = 0.044194173824159216f;  // 1/sqrt(512)
  for (int sub = 0; sub < JT / JS; ++sub) {
    int jbase = jt * JT + sub * JS;
    __syncthreads();  // covers qs-write (sub=0) and ks readers (sub>0)
    for (int s = tid; s < JS * 16; s += 256) {
      int j = s >> 4, qd = (s & 15) * 4;
      float4 t = *(const float4*)&k[((size_t)b * Lq + jbase + j) * Dq + h * DKq + qd];
      ks[j][qd] = t.x; ks[j][qd + 1] = t.y; ks[j][qd + 2] = t.z; ks[j][qd + 3] = t.w;
    }
    __syncthreads();
    float acc[3][2] = {};
    int j0 = jp * 2, j1 = j0 + 1;
#pragma unroll 8
    for (int d = 0; d < DKq; ++d) {
      float k0 = ks[j0][d], k1 = ks[j1][d];
#pragma unroll
      for (int uu = 0; uu < 3; ++uu) {
        float qv = qs[ug * 3 + uu][d];
        acc[uu][0] += qv * k0;
        acc[uu][1] += qv * k1;
      }
    }
#pragma unroll
    for (int uu = 0; uu < 3; ++uu) {
      int u = ug * 3 + uu;
      scg[((size_t)(bh * Uq + u)) * Lq + jbase + j0] = acc[uu][0] * scale;
      scg[((size_t)(bh * Uq + u)) * Lq + jbase + j1] = acc[uu][1] * scale;
    }
  }
}

// ---------------------------------------------------------------------------
// softmax over causal prefix + P@V; one block per (b,h,u)
// ---------------------------------------------------------------------------
__global__ __launch_bounds__(256) void softmax_pv(
    const float* __restrict__ scg, const float* __restrict__ v,
    const int* __restrict__ mtop, float* __restrict__ attnv) {
  __shared__ float es[Lq];      // exp(sc - mx)
  __shared__ float red[4][DKq];
  __shared__ float rr[4];
  int blk = blockIdx.x;  // bh*U + u
  int bh = blk / Uq;
  int h = bh & (Hq - 1);
  int b = bh >> 3;
  int tid = threadIdx.x, wave = tid >> 6, lane = tid & 63;
  int i0 = mtop[blk];
  int n = i0 + 1;  // causal: j <= i0
  const float* row = &scg[(size_t)blk * Lq];

  float mx = -INFINITY;
  for (int j = tid; j < n; j += 256) mx = fmaxf(mx, row[j]);
#pragma unroll
  for (int off = 32; off; off >>= 1) mx = fmaxf(mx, __shfl_xor(mx, off, 64));
  if (lane == 0) rr[wave] = mx;
  __syncthreads();
  mx = fmaxf(fmaxf(rr[0], rr[1]), fmaxf(rr[2], rr[3]));
  __syncthreads();  // all reads of rr done before rewrite

  float sm = 0.f;
  for (int j = tid; j < n; j += 256) {
    float e = __expf(row[j] - mx);
    es[j] = e;
    sm += e;
  }
#pragma unroll
  for (int off = 32; off; off >>= 1) sm += __shfl_xor(sm, off, 64);
  if (lane == 0) rr[wave] = sm;
  __syncthreads();  // covers es writes AND rr writes
  float inv = 1.0f / (rr[0] + rr[1] + rr[2] + rr[3]);

  float acc = 0.f;
  const float* vb = &v[(size_t)b * Lq * Dq + h * DKq + lane];
#pragma unroll 4
  for (int j = wave; j < n; j += 4) acc += es[j] * vb[(size_t)j * Dq];
  red[wave][lane] = acc;
  __syncthreads();
  if (wave == 0) {
    attnv[(size_t)blk * DKq + lane] =
        (red[0][lane] + red[1][lane] + red[2][lane] + red[3][lane]) * inv;
  }
}

// ---------------------------------------------------------------------------
// cumsum over L (tiled scan) + scatter of attn values + context build
// ---------------------------------------------------------------------------
__global__ __launch_bounds__(256) void tile_sum(const float* __restrict__ v,
                                                float* __restrict__ tsum) {
  int blk = blockIdx.x;  // B*NTILE
  int tile = blk & (NTILE - 1);
  int b = blk >> 4;
  int tid = threadIdx.x;
  for (int c = 0; c < Dq; c += 256) {
    int d = c + tid;
    float s = 0.f;
    for (int r = 0; r < TSCAN; ++r)
      s += v[((size_t)b * Lq + tile * TSCAN + r) * Dq + d];
    tsum[((size_t)b * NTILE + tile) * Dq + d] = s;
  }
}

__global__ void tile_prefix(float* __restrict__ tsum) {
  int t = blockIdx.x * blockDim.x + threadIdx.x;  // B*D
  if (t >= Bq * Dq) return;
  int b = t / Dq;
  int d = t % Dq;
  float run = 0.f;
  for (int i = 0; i < NTILE; ++i) {
    size_t off = ((size_t)b * NTILE + i) * Dq + d;
    float x = tsum[off];
    tsum[off] = run;
    run += x;
  }
}

__global__ __launch_bounds__(256) void build_context(
    const float* __restrict__ v, const float* __restrict__ tsum,
    const int* __restrict__ repl, const float* __restrict__ attnv,
    float* __restrict__ ctx) {
  int blk = blockIdx.x;  // B*NTILE
  int tile = blk & (NTILE - 1);
  int b = blk >> 4;
  int tid = threadIdx.x;
  for (int c = 0; c < Dq; c += 256) {
    int d = c + tid;
    int h = d >> 6;
    float run = tsum[((size_t)b * NTILE + tile) * Dq + d];
    for (int r = 0; r < TSCAN; ++r) {
      int l = tile * TSCAN + r;
      run += v[((size_t)b * Lq + l) * Dq + d];
      int u = repl[((size_t)(b * Hq + h)) * Lq + l];
      float val = (u >= 0)
                      ? attnv[(((size_t)(b * Hq + h)) * Uq + u) * DKq + (d & 63)]
                      : run;
      ctx[((size_t)b * Lq + l) * Dq + d] = val;
    }
  }
}

// ---------------------------------------------------------------------------
extern "C" void kernel_launch(void* const* d_in, const int* in_sizes, int n_in,
                              void* d_out, int out_size, void* d_ws,
                              size_t ws_size, hipStream_t stream) {
  const float* queries = (const float*)d_in[0];
  const float* keys    = (const float*)d_in[1];
  const float* values  = (const float*)d_in[2];
  const int*   idxs    = (const int*)d_in[3];
  const float* Wq = (const float*)d_in[4];
  const float* bq = (const float*)d_in[5];
  const float* Wk = (const float*)d_in[6];
  const float* bk = (const float*)d_in[7];
  const float* Wv = (const float*)d_in[8];
  const float* bv = (const float*)d_in[9];
  const float* Wo = (const float*)d_in[10];
  const float* bo = (const float*)d_in[11];
  float* out = (float*)d_out;

  const size_t BLD = (size_t)Bq * Lq * Dq;  // 4,194,304
  float* q     = (float*)d_ws;
  float* k     = q + BLD;
  float* v     = k + BLD;
  float* ctx   = v + BLD;
  float* m     = ctx + BLD;                        // B*H*L
  float* attnv = m + (size_t)Bq * Hq * Lq;         // B*H*U*DK
  float* tsum  = attnv + (size_t)Bq * Hq * Uq * DKq;  // B*NTILE*D
  int*   mtop  = (int*)(tsum + (size_t)Bq * NTILE * Dq);  // B*H*U
  int*   repl  = mtop + Bq * Hq * Uq;              // B*H*L
  // scores buffer aliases ctx: fully consumed by softmax_pv BEFORE
  // build_context writes ctx. (32*24*2048 = 1.57M floats < 4.19M)
  float* scg = ctx;

  dim3 ggrid(64, 8);  // M=8192/128, N=512/64

  // projections (fp32 — exact enough that top-k matches reference)
  gemm_bias<<<ggrid, 256, 0, stream>>>(queries, Wq, bq, q);
  gemm_bias<<<ggrid, 256, 0, stream>>>(keys, Wk, bk, k);
  gemm_bias<<<ggrid, 256, 0, stream>>>(values, Wv, bv, v);

  // sparsity metric + top-k
  compute_m<<<(Bq * Hq * Lq) / 4, 256, 0, stream>>>(q, k, idxs, m);
  topk_kernel<<<Bq * Hq, 256, 0, stream>>>(m, mtop);

  hipMemsetAsync(repl, 0xFF, (size_t)Bq * Hq * Lq * sizeof(int), stream);
  scatter_repl<<<3, 256, 0, stream>>>(mtop, repl);

  // attention on the top-24 rows: scores -> softmax + PV
  {
    dim3 sgrid(Lq / JT, Bq * Hq);  // (8, 32)
    scores_kernel<<<sgrid, 256, 0, stream>>>(q, k, mtop, scg);
  }
  softmax_pv<<<Bq * Hq * Uq, 256, 0, stream>>>(scg, v, mtop, attnv);

  // cumsum context + scatter
  tile_sum<<<Bq * NTILE, 256, 0, stream>>>(v, tsum);
  tile_prefix<<<(Bq * Dq + 255) / 256, 256, 0, stream>>>(tsum);
  build_context<<<Bq * NTILE, 256, 0, stream>>>(v, tsum, repl, attnv, ctx);

  // output projection
  gemm_bias<<<ggrid, 256, 0, stream>>>(ctx, Wo, bo, out);
}

// Round 3
// 416.708 us; speedup vs baseline: 2.1373x; 1.4439x over previous
//
#include <hip/hip_runtime.h>
#include <hip/hip_bf16.h>
#include <math.h>

#define Bq 4
#define Lq 2048
#define Dq 512
#define Hq 8
#define DKq 64
#define Uq 24
#define TSCAN 128
#define NTILE (Lq / TSCAN)   // 16

typedef unsigned short ushort_t;
typedef __attribute__((ext_vector_type(8))) short bfrag8;   // 8 bf16 (4 VGPRs)
typedef __attribute__((ext_vector_type(4))) float facc4;    // MFMA accumulator

__device__ inline ushort_t bf16_rne(float f) {
  unsigned u = __float_as_uint(f);
  u += 0x7FFF + ((u >> 16) & 1);
  return (ushort_t)(u >> 16);
}
__device__ inline float bf16f(ushort_t h) {
  return __uint_as_float(((unsigned)h) << 16);
}

// ---------------------------------------------------------------------------
// cast fp32 -> (bf16 hi, bf16 lo) elementwise; lo = rne(x - hi)
// ---------------------------------------------------------------------------
__global__ __launch_bounds__(256) void cast_hilo(
    const float* __restrict__ x, ushort_t* __restrict__ hi,
    ushort_t* __restrict__ lo, int n4) {
  int t = blockIdx.x * 256 + threadIdx.x;
  if (t >= n4) return;
  float4 v = *(const float4*)&x[(size_t)t * 4];
  ushort_t h0 = bf16_rne(v.x), h1 = bf16_rne(v.y), h2 = bf16_rne(v.z),
           h3 = bf16_rne(v.w);
  ushort4 hh = {h0, h1, h2, h3};
  ushort4 ll = {bf16_rne(v.x - bf16f(h0)), bf16_rne(v.y - bf16f(h1)),
                bf16_rne(v.z - bf16f(h2)), bf16_rne(v.w - bf16f(h3))};
  *(ushort4*)&hi[(size_t)t * 4] = hh;
  *(ushort4*)&lo[(size_t)t * 4] = ll;
}

// ---------------------------------------------------------------------------
// W[512][512] fp32 -> Wt hi/lo bf16 [n][k] (transposed, 32x32 LDS tiles)
// ---------------------------------------------------------------------------
__global__ __launch_bounds__(256) void transpose_cast(
    const float* __restrict__ W, ushort_t* __restrict__ Th,
    ushort_t* __restrict__ Tl) {
  __shared__ float tile[32][33];
  int k0 = blockIdx.x * 32, n0 = blockIdx.y * 32;
  int tx = threadIdx.x & 31, ty = threadIdx.x >> 5;  // ty 0..7
  for (int r = ty; r < 32; r += 8)
    tile[tx][r] = W[(size_t)(k0 + r) * 512 + n0 + tx];
  __syncthreads();
  for (int r = ty; r < 32; r += 8) {
    float v = tile[r][tx];
    ushort_t h = bf16_rne(v);
    Th[(size_t)(n0 + r) * 512 + k0 + tx] = h;
    Tl[(size_t)(n0 + r) * 512 + k0 + tx] = bf16_rne(v - bf16f(h));
  }
}

// ---------------------------------------------------------------------------
// bf16 MFMA GEMM (hi only): C[8192x512] = A @ Bt^T + bias
// A [M][K] bf16, Bt [N][K] bf16 (pre-transposed W). 128x64 tile, 4 waves.
// ---------------------------------------------------------------------------
__global__ __launch_bounds__(256) void gemm_bf16(
    const ushort_t* __restrict__ A, const ushort_t* __restrict__ Bt,
    const float* __restrict__ bias, float* __restrict__ C) {
  __shared__ ushort_t As[128][32];  // 8 KB  [m][k]
  __shared__ ushort_t Bs[64][32];   // 4 KB  [n][k]
  int bm = blockIdx.x, bn = blockIdx.y;
  int tid = threadIdx.x;
  int wave = tid >> 6, lane = tid & 63;
  int wm = (wave & 1) * 64, wn = (wave >> 1) * 32;
  int quad = lane >> 4, lm = lane & 15;
  facc4 acc[4][2] = {};

  for (int k0 = 0; k0 < 512; k0 += 32) {
#pragma unroll
    for (int p = 0; p < 2; ++p) {
      int s = p * 256 + tid;
      int row = s >> 2, kq = (s & 3) * 8;
      *(bfrag8*)&As[row][kq] =
          *(const bfrag8*)&A[(size_t)(bm * 128 + row) * 512 + k0 + kq];
    }
    {
      int row = tid >> 2, kq = (tid & 3) * 8;
      *(bfrag8*)&Bs[row][kq] =
          *(const bfrag8*)&Bt[(size_t)(bn * 64 + row) * 512 + k0 + kq];
    }
    __syncthreads();
    bfrag8 af[4], bf[2];
#pragma unroll
    for (int mt = 0; mt < 4; ++mt)
      af[mt] = *(bfrag8*)&As[wm + mt * 16 + lm][quad * 8];
#pragma unroll
    for (int nt = 0; nt < 2; ++nt)
      bf[nt] = *(bfrag8*)&Bs[wn + nt * 16 + lm][quad * 8];
#pragma unroll
    for (int mt = 0; mt < 4; ++mt)
#pragma unroll
      for (int nt = 0; nt < 2; ++nt)
        acc[mt][nt] = __builtin_amdgcn_mfma_f32_16x16x32_bf16(
            af[mt], bf[nt], acc[mt][nt], 0, 0, 0);
    __syncthreads();
  }
#pragma unroll
  for (int mt = 0; mt < 4; ++mt)
#pragma unroll
    for (int nt = 0; nt < 2; ++nt) {
      int col = bn * 64 + wn + nt * 16 + lm;
      float bv = bias[col];
#pragma unroll
      for (int r = 0; r < 4; ++r) {
        int row = bm * 128 + wm + mt * 16 + quad * 4 + r;
        C[(size_t)row * 512 + col] = acc[mt][nt][r] + bv;
      }
    }
}

// ---------------------------------------------------------------------------
// split-bf16 MFMA GEMM: C = (Ah+Al) @ (Bh+Bl)^T + bias, skipping Al*Bl.
// ~2^-17 relative accuracy — preserves top-k ordering downstream.
// ---------------------------------------------------------------------------
__global__ __launch_bounds__(256) void gemm_split(
    const ushort_t* __restrict__ Ah, const ushort_t* __restrict__ Al,
    const ushort_t* __restrict__ Bth, const ushort_t* __restrict__ Btl,
    const float* __restrict__ bias, float* __restrict__ C) {
  __shared__ ushort_t Ash[128][32], Asl[128][32];  // 16 KB
  __shared__ ushort_t Bsh[64][32], Bsl[64][32];    // 8 KB
  int bm = blockIdx.x, bn = blockIdx.y;
  int tid = threadIdx.x;
  int wave = tid >> 6, lane = tid & 63;
  int wm = (wave & 1) * 64, wn = (wave >> 1) * 32;
  int quad = lane >> 4, lm = lane & 15;
  facc4 acc[4][2] = {};

  for (int k0 = 0; k0 < 512; k0 += 32) {
#pragma unroll
    for (int p = 0; p < 2; ++p) {
      int s = p * 256 + tid;
      int row = s >> 2, kq = (s & 3) * 8;
      size_t g = (size_t)(bm * 128 + row) * 512 + k0 + kq;
      *(bfrag8*)&Ash[row][kq] = *(const bfrag8*)&Ah[g];
      *(bfrag8*)&Asl[row][kq] = *(const bfrag8*)&Al[g];
    }
    {
      int row = tid >> 2, kq = (tid & 3) * 8;
      size_t g = (size_t)(bn * 64 + row) * 512 + k0 + kq;
      *(bfrag8*)&Bsh[row][kq] = *(const bfrag8*)&Bth[g];
      *(bfrag8*)&Bsl[row][kq] = *(const bfrag8*)&Btl[g];
    }
    __syncthreads();
    bfrag8 afh[4], afl[4], bfh[2], bfl[2];
#pragma unroll
    for (int mt = 0; mt < 4; ++mt) {
      afh[mt] = *(bfrag8*)&Ash[wm + mt * 16 + lm][quad * 8];
      afl[mt] = *(bfrag8*)&Asl[wm + mt * 16 + lm][quad * 8];
    }
#pragma unroll
    for (int nt = 0; nt < 2; ++nt) {
      bfh[nt] = *(bfrag8*)&Bsh[wn + nt * 16 + lm][quad * 8];
      bfl[nt] = *(bfrag8*)&Bsl[wn + nt * 16 + lm][quad * 8];
    }
#pragma unroll
    for (int mt = 0; mt < 4; ++mt)
#pragma unroll
      for (int nt = 0; nt < 2; ++nt) {
        facc4 a = acc[mt][nt];
        a = __builtin_amdgcn_mfma_f32_16x16x32_bf16(afh[mt], bfh[nt], a, 0, 0, 0);
        a = __builtin_amdgcn_mfma_f32_16x16x32_bf16(afl[mt], bfh[nt], a, 0, 0, 0);
        a = __builtin_amdgcn_mfma_f32_16x16x32_bf16(afh[mt], bfl[nt], a, 0, 0, 0);
        acc[mt][nt] = a;
      }
    __syncthreads();
  }
#pragma unroll
  for (int mt = 0; mt < 4; ++mt)
#pragma unroll
    for (int nt = 0; nt < 2; ++nt) {
      int col = bn * 64 + wn + nt * 16 + lm;
      float bv = bias[col];
#pragma unroll
      for (int r = 0; r < 4; ++r) {
        int row = bm * 128 + wm + mt * 16 + quad * 4 + r;
        C[(size_t)row * 512 + col] = acc[mt][nt][r] + bv;
      }
    }
}

// ---------------------------------------------------------------------------
// m[b,h,l] = max_s(q.k_sample) - sum_s(q.k_sample)/L
// 16 lanes per l (one float4 of d each), 4 l per wave: 6x fewer shuffles.
// ---------------------------------------------------------------------------
__global__ __launch_bounds__(256) void compute_m(
    const float* __restrict__ q, const float* __restrict__ k,
    const int* __restrict__ idxs, float* __restrict__ m) {
  int wave = threadIdx.x >> 6, lane = threadIdx.x & 63;
  int lq = lane >> 4, dq = lane & 15;
  int slot = (blockIdx.x * 4 + wave) * 4 + lq;  // (b,h,l) flat
  int l = slot & (Lq - 1);
  int bh = slot >> 11;
  int h = bh & (Hq - 1), b = bh >> 3;
  float4 qv = *(const float4*)&q[((size_t)b * Lq + l) * Dq + h * DKq + dq * 4];
  const float* kb = &k[(size_t)b * Lq * Dq + h * DKq + dq * 4];
  const int* ib = &idxs[l * Uq];
  float mx = -INFINITY, sm = 0.f;
#pragma unroll
  for (int s = 0; s < Uq; ++s) {
    int j = ib[s];
    float4 kv = *(const float4*)&kb[(size_t)j * Dq];
    float p = qv.x * kv.x + qv.y * kv.y + qv.z * kv.z + qv.w * kv.w;
    p += __shfl_xor(p, 1, 64);
    p += __shfl_xor(p, 2, 64);
    p += __shfl_xor(p, 4, 64);
    p += __shfl_xor(p, 8, 64);
    mx = fmaxf(mx, p);
    sm += p;
  }
  if (dq == 0) m[slot] = mx - sm * (1.0f / Lq);
}

// ---------------------------------------------------------------------------
// top-24 per (b,h): iterative argmax, tie-break smaller index (lax.top_k)
// ---------------------------------------------------------------------------
__global__ __launch_bounds__(256) void topk_kernel(
    const float* __restrict__ m, int* __restrict__ mtop) {
  __shared__ float vals[Lq];
  __shared__ float rv[256];
  __shared__ int ri[256];
  int bh = blockIdx.x;
  int tid = threadIdx.x;
  for (int i = tid; i < Lq; i += 256) vals[i] = m[(size_t)bh * Lq + i];
  __syncthreads();
  for (int t = 0; t < Uq; ++t) {
    float best = -INFINITY;
    int bi = Lq;
    for (int i = tid; i < Lq; i += 256) {
      float v = vals[i];
      if (v > best || (v == best && i < bi)) { best = v; bi = i; }
    }
    rv[tid] = best;
    ri[tid] = bi;
    __syncthreads();
    for (int s = 128; s; s >>= 1) {
      if (tid < s) {
        float ov = rv[tid + s];
        int oi = ri[tid + s];
        if (ov > rv[tid] || (ov == rv[tid] && oi < ri[tid])) {
          rv[tid] = ov;
          ri[tid] = oi;
        }
      }
      __syncthreads();
    }
    if (tid == 0) {
      mtop[bh * Uq + t] = ri[0];
      vals[ri[0]] = -INFINITY;
    }
    __syncthreads();
  }
}

// repl[b,h,l] = u if l == mtop[b,h,u] else -1 (table pre-filled with -1)
__global__ void scatter_repl(const int* __restrict__ mtop, int* __restrict__ repl) {
  int t = blockIdx.x * blockDim.x + threadIdx.x;
  if (t < Bq * Hq * Uq) {
    int bh = t / Uq;
    repl[(size_t)bh * Lq + mtop[t]] = t % Uq;
  }
}

// ---------------------------------------------------------------------------
// scores[bh][u][j] = (q[b,i0[u],h,:] . k[b,j,h,:]) / sqrt(D)
// ---------------------------------------------------------------------------
#define JT 256
#define JS 64

__global__ __launch_bounds__(256) void scores_kernel(
    const float* __restrict__ q, const float* __restrict__ k,
    const int* __restrict__ mtop, float* __restrict__ scg) {
  __shared__ float qs[Uq][DKq + 1];
  __shared__ float ks[JS][DKq + 1];
  __shared__ int i0s[Uq];
  int bh = blockIdx.y;
  int jt = blockIdx.x;
  int h = bh & (Hq - 1);
  int b = bh >> 3;
  int tid = threadIdx.x;
  if (tid < Uq) i0s[tid] = mtop[bh * Uq + tid];
  __syncthreads();
  for (int s = tid; s < Uq * 16; s += 256) {
    int u = s >> 4, qd = (s & 15) * 4;
    float4 t = *(const float4*)&q[((size_t)b * Lq + i0s[u]) * Dq + h * DKq + qd];
    qs[u][qd] = t.x; qs[u][qd + 1] = t.y; qs[u][qd + 2] = t.z; qs[u][qd + 3] = t.w;
  }
  int jp = tid & 31;
  int ug = tid >> 5;
  const float scale = 0.044194173824159216f;  // 1/sqrt(512)
  for (int sub = 0; sub < JT / JS; ++sub) {
    int jbase = jt * JT + sub * JS;
    __syncthreads();
    for (int s = tid; s < JS * 16; s += 256) {
      int j = s >> 4, qd = (s & 15) * 4;
      float4 t = *(const float4*)&k[((size_t)b * Lq + jbase + j) * Dq + h * DKq + qd];
      ks[j][qd] = t.x; ks[j][qd + 1] = t.y; ks[j][qd + 2] = t.z; ks[j][qd + 3] = t.w;
    }
    __syncthreads();
    float acc[3][2] = {};
    int j0 = jp * 2, j1 = j0 + 1;
#pragma unroll 8
    for (int d = 0; d < DKq; ++d) {
      float k0 = ks[j0][d], k1 = ks[j1][d];
#pragma unroll
      for (int uu = 0; uu < 3; ++uu) {
        float qv = qs[ug * 3 + uu][d];
        acc[uu][0] += qv * k0;
        acc[uu][1] += qv * k1;
      }
    }
#pragma unroll
    for (int uu = 0; uu < 3; ++uu) {
      int u = ug * 3 + uu;
      scg[((size_t)(bh * Uq + u)) * Lq + jbase + j0] = acc[uu][0] * scale;
      scg[((size_t)(bh * Uq + u)) * Lq + jbase + j1] = acc[uu][1] * scale;
    }
  }
}

// ---------------------------------------------------------------------------
// softmax over causal prefix + P@V; one block per (b,h,u)
// ---------------------------------------------------------------------------
__global__ __launch_bounds__(256) void softmax_pv(
    const float* __restrict__ scg, const float* __restrict__ v,
    const int* __restrict__ mtop, float* __restrict__ attnv) {
  __shared__ float es[Lq];
  __shared__ float red[4][DKq];
  __shared__ float rr[4];
  int blk = blockIdx.x;
  int bh = blk / Uq;
  int h = bh & (Hq - 1);
  int b = bh >> 3;
  int tid = threadIdx.x, wave = tid >> 6, lane = tid & 63;
  int i0 = mtop[blk];
  int n = i0 + 1;
  const float* row = &scg[(size_t)blk * Lq];

  float mx = -INFINITY;
  for (int j = tid; j < n; j += 256) mx = fmaxf(mx, row[j]);
#pragma unroll
  for (int off = 32; off; off >>= 1) mx = fmaxf(mx, __shfl_xor(mx, off, 64));
  if (lane == 0) rr[wave] = mx;
  __syncthreads();
  mx = fmaxf(fmaxf(rr[0], rr[1]), fmaxf(rr[2], rr[3]));
  __syncthreads();

  float sm = 0.f;
  for (int j = tid; j < n; j += 256) {
    float e = __expf(row[j] - mx);
    es[j] = e;
    sm += e;
  }
#pragma unroll
  for (int off = 32; off; off >>= 1) sm += __shfl_xor(sm, off, 64);
  if (lane == 0) rr[wave] = sm;
  __syncthreads();
  float inv = 1.0f / (rr[0] + rr[1] + rr[2] + rr[3]);

  float acc = 0.f;
  const float* vb = &v[(size_t)b * Lq * Dq + h * DKq + lane];
#pragma unroll 4
  for (int j = wave; j < n; j += 4) acc += es[j] * vb[(size_t)j * Dq];
  red[wave][lane] = acc;
  __syncthreads();
  if (wave == 0) {
    attnv[(size_t)blk * DKq + lane] =
        (red[0][lane] + red[1][lane] + red[2][lane] + red[3][lane]) * inv;
  }
}

// ---------------------------------------------------------------------------
// cumsum over L (tiled scan) + scatter of attn values + context build
// ---------------------------------------------------------------------------
__global__ __launch_bounds__(256) void tile_sum(const float* __restrict__ v,
                                                float* __restrict__ tsum) {
  int blk = blockIdx.x;
  int tile = blk & (NTILE - 1);
  int b = blk >> 4;
  int tid = threadIdx.x;
  for (int c = 0; c < Dq; c += 256) {
    int d = c + tid;
    float s = 0.f;
    for (int r = 0; r < TSCAN; ++r)
      s += v[((size_t)b * Lq + tile * TSCAN + r) * Dq + d];
    tsum[((size_t)b * NTILE + tile) * Dq + d] = s;
  }
}

__global__ void tile_prefix(float* __restrict__ tsum) {
  int t = blockIdx.x * blockDim.x + threadIdx.x;
  if (t >= Bq * Dq) return;
  int b = t / Dq;
  int d = t % Dq;
  float run = 0.f;
  for (int i = 0; i < NTILE; ++i) {
    size_t off = ((size_t)b * NTILE + i) * Dq + d;
    float x = tsum[off];
    tsum[off] = run;
    run += x;
  }
}

__global__ __launch_bounds__(256) void build_context(
    const float* __restrict__ v, const float* __restrict__ tsum,
    const int* __restrict__ repl, const float* __restrict__ attnv,
    float* __restrict__ ctx) {
  int blk = blockIdx.x;
  int tile = blk & (NTILE - 1);
  int b = blk >> 4;
  int tid = threadIdx.x;
  for (int c = 0; c < Dq; c += 256) {
    int d = c + tid;
    int h = d >> 6;
    float run = tsum[((size_t)b * NTILE + tile) * Dq + d];
    for (int r = 0; r < TSCAN; ++r) {
      int l = tile * TSCAN + r;
      run += v[((size_t)b * Lq + l) * Dq + d];
      int u = repl[((size_t)(b * Hq + h)) * Lq + l];
      float val = (u >= 0)
                      ? attnv[(((size_t)(b * Hq + h)) * Uq + u) * DKq + (d & 63)]
                      : run;
      ctx[((size_t)b * Lq + l) * Dq + d] = val;
    }
  }
}

// ---------------------------------------------------------------------------
extern "C" void kernel_launch(void* const* d_in, const int* in_sizes, int n_in,
                              void* d_out, int out_size, void* d_ws,
                              size_t ws_size, hipStream_t stream) {
  const float* queries = (const float*)d_in[0];
  const float* keys    = (const float*)d_in[1];
  const float* values  = (const float*)d_in[2];
  const int*   idxs    = (const int*)d_in[3];
  const float* Wq = (const float*)d_in[4];
  const float* bq = (const float*)d_in[5];
  const float* Wk = (const float*)d_in[6];
  const float* bk = (const float*)d_in[7];
  const float* Wv = (const float*)d_in[8];
  const float* bv = (const float*)d_in[9];
  const float* Wo = (const float*)d_in[10];
  const float* bo = (const float*)d_in[11];
  float* out = (float*)d_out;

  const size_t BLD = (size_t)Bq * Lq * Dq;  // 4,194,304
  char* w = (char*)d_ws;
  float* q    = (float*)w; w += BLD * 4;
  float* k    = (float*)w; w += BLD * 4;
  float* v    = (float*)w; w += BLD * 4;
  float* ctx  = (float*)w; w += BLD * 4;
  float* m    = (float*)w; w += (size_t)Bq * Hq * Lq * 4;
  float* attnv= (float*)w; w += (size_t)Bq * Hq * Uq * DKq * 4;
  float* tsum = (float*)w; w += (size_t)Bq * NTILE * Dq * 4;
  int* mtop   = (int*)w;   w += Bq * Hq * Uq * 4;
  int* repl   = (int*)w;   w += (size_t)Bq * Hq * Lq * 4;
  ushort_t* Ah = (ushort_t*)w; w += BLD * 2;   // reused across all 4 GEMMs
  ushort_t* Al = (ushort_t*)w; w += BLD * 2;
  const size_t WSZ = 512 * 512;
  ushort_t* Wqh = (ushort_t*)w; w += WSZ * 2;
  ushort_t* Wql = (ushort_t*)w; w += WSZ * 2;
  ushort_t* Wkh = (ushort_t*)w; w += WSZ * 2;
  ushort_t* Wkl = (ushort_t*)w; w += WSZ * 2;
  ushort_t* Wvh = (ushort_t*)w; w += WSZ * 2;
  ushort_t* Wvl = (ushort_t*)w; w += WSZ * 2;
  ushort_t* Woh = (ushort_t*)w; w += WSZ * 2;
  ushort_t* Wol = (ushort_t*)w; w += WSZ * 2;
  float* scg = ctx;  // scores alias ctx (consumed before ctx written)

  dim3 tgrid(16, 16);
  transpose_cast<<<tgrid, 256, 0, stream>>>(Wq, Wqh, Wql);
  transpose_cast<<<tgrid, 256, 0, stream>>>(Wk, Wkh, Wkl);
  transpose_cast<<<tgrid, 256, 0, stream>>>(Wv, Wvh, Wvl);
  transpose_cast<<<tgrid, 256, 0, stream>>>(Wo, Woh, Wol);

  dim3 ggrid(64, 8);  // M=8192/128, N=512/64
  const int CAST_B = (int)(BLD / 4 / 256);  // 4096 blocks

  // Q/K projections: split-bf16 (top-k-safe). V: plain bf16.
  cast_hilo<<<CAST_B, 256, 0, stream>>>(queries, Ah, Al, (int)(BLD / 4));
  gemm_split<<<ggrid, 256, 0, stream>>>(Ah, Al, Wqh, Wql, bq, q);
  cast_hilo<<<CAST_B, 256, 0, stream>>>(keys, Ah, Al, (int)(BLD / 4));
  gemm_split<<<ggrid, 256, 0, stream>>>(Ah, Al, Wkh, Wkl, bk, k);
  cast_hilo<<<CAST_B, 256, 0, stream>>>(values, Ah, Al, (int)(BLD / 4));
  gemm_bf16<<<ggrid, 256, 0, stream>>>(Ah, Wvh, bv, v);

  // sparsity metric + top-k
  compute_m<<<(Bq * Hq * Lq) / 16, 256, 0, stream>>>(q, k, idxs, m);
  topk_kernel<<<Bq * Hq, 256, 0, stream>>>(m, mtop);

  hipMemsetAsync(repl, 0xFF, (size_t)Bq * Hq * Lq * sizeof(int), stream);
  scatter_repl<<<3, 256, 0, stream>>>(mtop, repl);

  // attention on the top-24 rows
  {
    dim3 sgrid(Lq / JT, Bq * Hq);  // (8, 32)
    scores_kernel<<<sgrid, 256, 0, stream>>>(q, k, mtop, scg);
  }
  softmax_pv<<<Bq * Hq * Uq, 256, 0, stream>>>(scg, v, mtop, attnv);

  // cumsum context + scatter
  tile_sum<<<Bq * NTILE, 256, 0, stream>>>(v, tsum);
  tile_prefix<<<(Bq * Dq + 255) / 256, 256, 0, stream>>>(tsum);
  build_context<<<Bq * NTILE, 256, 0, stream>>>(v, tsum, repl, attnv, ctx);

  // output projection (plain bf16)
  cast_hilo<<<CAST_B, 256, 0, stream>>>(ctx, Ah, Al, (int)(BLD / 4));
  gemm_bf16<<<ggrid, 256, 0, stream>>>(Ah, Woh, bo, out);
}

// Round 4
// 370.238 us; speedup vs baseline: 2.4056x; 1.1255x over previous
//
#include <hip/hip_runtime.h>
#include <hip/hip_bf16.h>
#include <math.h>

#define Bq 4
#define Lq 2048
#define Dq 512
#define Hq 8
#define DKq 64
#define Uq 24
#define TSCAN 16
#define NTILE (Lq / TSCAN)   // 128

typedef unsigned short ushort_t;
typedef __attribute__((ext_vector_type(8))) short bfrag8;   // 8 bf16 (4 VGPRs)
typedef __attribute__((ext_vector_type(4))) float facc4;    // MFMA accumulator

__device__ inline ushort_t bf16_rne(float f) {
  unsigned u = __float_as_uint(f);
  u += 0x7FFF + ((u >> 16) & 1);
  return (ushort_t)(u >> 16);
}
__device__ inline float bf16f(ushort_t h) {
  return __uint_as_float(((unsigned)h) << 16);
}

// ---------------------------------------------------------------------------
// cast fp32 -> (bf16 hi, bf16 lo) elementwise; lo = rne(x - hi)
// ---------------------------------------------------------------------------
__global__ __launch_bounds__(256) void cast_hilo(
    const float* __restrict__ x, ushort_t* __restrict__ hi,
    ushort_t* __restrict__ lo, int n4) {
  int t = blockIdx.x * 256 + threadIdx.x;
  if (t >= n4) return;
  float4 v = *(const float4*)&x[(size_t)t * 4];
  ushort_t h0 = bf16_rne(v.x), h1 = bf16_rne(v.y), h2 = bf16_rne(v.z),
           h3 = bf16_rne(v.w);
  ushort4 hh = {h0, h1, h2, h3};
  ushort4 ll = {bf16_rne(v.x - bf16f(h0)), bf16_rne(v.y - bf16f(h1)),
                bf16_rne(v.z - bf16f(h2)), bf16_rne(v.w - bf16f(h3))};
  *(ushort4*)&hi[(size_t)t * 4] = hh;
  *(ushort4*)&lo[(size_t)t * 4] = ll;
}

// ---------------------------------------------------------------------------
// W[512][512] fp32 -> Wt hi/lo bf16 [n][k] (transposed, 32x32 LDS tiles)
// ---------------------------------------------------------------------------
__global__ __launch_bounds__(256) void transpose_cast(
    const float* __restrict__ W, ushort_t* __restrict__ Th,
    ushort_t* __restrict__ Tl) {
  __shared__ float tile[32][33];
  int k0 = blockIdx.x * 32, n0 = blockIdx.y * 32;
  int tx = threadIdx.x & 31, ty = threadIdx.x >> 5;  // ty 0..7
  for (int r = ty; r < 32; r += 8)
    tile[tx][r] = W[(size_t)(k0 + r) * 512 + n0 + tx];
  __syncthreads();
  for (int r = ty; r < 32; r += 8) {
    float v = tile[r][tx];
    ushort_t h = bf16_rne(v);
    Th[(size_t)(n0 + r) * 512 + k0 + tx] = h;
    Tl[(size_t)(n0 + r) * 512 + k0 + tx] = bf16_rne(v - bf16f(h));
  }
}

// ---------------------------------------------------------------------------
// bf16 MFMA GEMM (hi only): C[8192x512] = A @ Bt^T + bias
// ---------------------------------------------------------------------------
__global__ __launch_bounds__(256) void gemm_bf16(
    const ushort_t* __restrict__ A, const ushort_t* __restrict__ Bt,
    const float* __restrict__ bias, float* __restrict__ C) {
  __shared__ ushort_t As[128][32];  // 8 KB  [m][k]
  __shared__ ushort_t Bs[64][32];   // 4 KB  [n][k]
  int bm = blockIdx.x, bn = blockIdx.y;
  int tid = threadIdx.x;
  int wave = tid >> 6, lane = tid & 63;
  int wm = (wave & 1) * 64, wn = (wave >> 1) * 32;
  int quad = lane >> 4, lm = lane & 15;
  facc4 acc[4][2] = {};

  for (int k0 = 0; k0 < 512; k0 += 32) {
#pragma unroll
    for (int p = 0; p < 2; ++p) {
      int s = p * 256 + tid;
      int row = s >> 2, kq = (s & 3) * 8;
      *(bfrag8*)&As[row][kq] =
          *(const bfrag8*)&A[(size_t)(bm * 128 + row) * 512 + k0 + kq];
    }
    {
      int row = tid >> 2, kq = (tid & 3) * 8;
      *(bfrag8*)&Bs[row][kq] =
          *(const bfrag8*)&Bt[(size_t)(bn * 64 + row) * 512 + k0 + kq];
    }
    __syncthreads();
    bfrag8 af[4], bf[2];
#pragma unroll
    for (int mt = 0; mt < 4; ++mt)
      af[mt] = *(bfrag8*)&As[wm + mt * 16 + lm][quad * 8];
#pragma unroll
    for (int nt = 0; nt < 2; ++nt)
      bf[nt] = *(bfrag8*)&Bs[wn + nt * 16 + lm][quad * 8];
#pragma unroll
    for (int mt = 0; mt < 4; ++mt)
#pragma unroll
      for (int nt = 0; nt < 2; ++nt)
        acc[mt][nt] = __builtin_amdgcn_mfma_f32_16x16x32_bf16(
            af[mt], bf[nt], acc[mt][nt], 0, 0, 0);
    __syncthreads();
  }
#pragma unroll
  for (int mt = 0; mt < 4; ++mt)
#pragma unroll
    for (int nt = 0; nt < 2; ++nt) {
      int col = bn * 64 + wn + nt * 16 + lm;
      float bv = bias[col];
#pragma unroll
      for (int r = 0; r < 4; ++r) {
        int row = bm * 128 + wm + mt * 16 + quad * 4 + r;
        C[(size_t)row * 512 + col] = acc[mt][nt][r] + bv;
      }
    }
}

// ---------------------------------------------------------------------------
// split-bf16 MFMA GEMM: C = (Ah+Al) @ (Bh+Bl)^T + bias, skipping Al*Bl.
// ---------------------------------------------------------------------------
__global__ __launch_bounds__(256) void gemm_split(
    const ushort_t* __restrict__ Ah, const ushort_t* __restrict__ Al,
    const ushort_t* __restrict__ Bth, const ushort_t* __restrict__ Btl,
    const float* __restrict__ bias, float* __restrict__ C) {
  __shared__ ushort_t Ash[128][32], Asl[128][32];  // 16 KB
  __shared__ ushort_t Bsh[64][32], Bsl[64][32];    // 8 KB
  int bm = blockIdx.x, bn = blockIdx.y;
  int tid = threadIdx.x;
  int wave = tid >> 6, lane = tid & 63;
  int wm = (wave & 1) * 64, wn = (wave >> 1) * 32;
  int quad = lane >> 4, lm = lane & 15;
  facc4 acc[4][2] = {};

  for (int k0 = 0; k0 < 512; k0 += 32) {
#pragma unroll
    for (int p = 0; p < 2; ++p) {
      int s = p * 256 + tid;
      int row = s >> 2, kq = (s & 3) * 8;
      size_t g = (size_t)(bm * 128 + row) * 512 + k0 + kq;
      *(bfrag8*)&Ash[row][kq] = *(const bfrag8*)&Ah[g];
      *(bfrag8*)&Asl[row][kq] = *(const bfrag8*)&Al[g];
    }
    {
      int row = tid >> 2, kq = (tid & 3) * 8;
      size_t g = (size_t)(bn * 64 + row) * 512 + k0 + kq;
      *(bfrag8*)&Bsh[row][kq] = *(const bfrag8*)&Bth[g];
      *(bfrag8*)&Bsl[row][kq] = *(const bfrag8*)&Btl[g];
    }
    __syncthreads();
    bfrag8 afh[4], afl[4], bfh[2], bfl[2];
#pragma unroll
    for (int mt = 0; mt < 4; ++mt) {
      afh[mt] = *(bfrag8*)&Ash[wm + mt * 16 + lm][quad * 8];
      afl[mt] = *(bfrag8*)&Asl[wm + mt * 16 + lm][quad * 8];
    }
#pragma unroll
    for (int nt = 0; nt < 2; ++nt) {
      bfh[nt] = *(bfrag8*)&Bsh[wn + nt * 16 + lm][quad * 8];
      bfl[nt] = *(bfrag8*)&Bsl[wn + nt * 16 + lm][quad * 8];
    }
#pragma unroll
    for (int mt = 0; mt < 4; ++mt)
#pragma unroll
      for (int nt = 0; nt < 2; ++nt) {
        facc4 a = acc[mt][nt];
        a = __builtin_amdgcn_mfma_f32_16x16x32_bf16(afh[mt], bfh[nt], a, 0, 0, 0);
        a = __builtin_amdgcn_mfma_f32_16x16x32_bf16(afl[mt], bfh[nt], a, 0, 0, 0);
        a = __builtin_amdgcn_mfma_f32_16x16x32_bf16(afh[mt], bfl[nt], a, 0, 0, 0);
        acc[mt][nt] = a;
      }
    __syncthreads();
  }
#pragma unroll
  for (int mt = 0; mt < 4; ++mt)
#pragma unroll
    for (int nt = 0; nt < 2; ++nt) {
      int col = bn * 64 + wn + nt * 16 + lm;
      float bv = bias[col];
#pragma unroll
      for (int r = 0; r < 4; ++r) {
        int row = bm * 128 + wm + mt * 16 + quad * 4 + r;
        C[(size_t)row * 512 + col] = acc[mt][nt][r] + bv;
      }
    }
}

// ---------------------------------------------------------------------------
// m[b,h,l] = max_s(q.k_sample) - sum_s(q.k_sample)/L
// ---------------------------------------------------------------------------
__global__ __launch_bounds__(256) void compute_m(
    const float* __restrict__ q, const float* __restrict__ k,
    const int* __restrict__ idxs, float* __restrict__ m) {
  int wave = threadIdx.x >> 6, lane = threadIdx.x & 63;
  int lq = lane >> 4, dq = lane & 15;
  int slot = (blockIdx.x * 4 + wave) * 4 + lq;  // (b,h,l) flat
  int l = slot & (Lq - 1);
  int bh = slot >> 11;
  int h = bh & (Hq - 1), b = bh >> 3;
  float4 qv = *(const float4*)&q[((size_t)b * Lq + l) * Dq + h * DKq + dq * 4];
  const float* kb = &k[(size_t)b * Lq * Dq + h * DKq + dq * 4];
  const int* ib = &idxs[l * Uq];
  float mx = -INFINITY, sm = 0.f;
#pragma unroll
  for (int s = 0; s < Uq; ++s) {
    int j = ib[s];
    float4 kv = *(const float4*)&kb[(size_t)j * Dq];
    float p = qv.x * kv.x + qv.y * kv.y + qv.z * kv.z + qv.w * kv.w;
    p += __shfl_xor(p, 1, 64);
    p += __shfl_xor(p, 2, 64);
    p += __shfl_xor(p, 4, 64);
    p += __shfl_xor(p, 8, 64);
    mx = fmaxf(mx, p);
    sm += p;
  }
  if (dq == 0) m[slot] = mx - sm * (1.0f / Lq);
}

// ---------------------------------------------------------------------------
// top-24 per (b,h): iterative argmax, tie-break smaller index (lax.top_k)
// ---------------------------------------------------------------------------
__global__ __launch_bounds__(256) void topk_kernel(
    const float* __restrict__ m, int* __restrict__ mtop) {
  __shared__ float vals[Lq];
  __shared__ float rv[256];
  __shared__ int ri[256];
  int bh = blockIdx.x;
  int tid = threadIdx.x;
  for (int i = tid; i < Lq; i += 256) vals[i] = m[(size_t)bh * Lq + i];
  __syncthreads();
  for (int t = 0; t < Uq; ++t) {
    float best = -INFINITY;
    int bi = Lq;
    for (int i = tid; i < Lq; i += 256) {
      float v = vals[i];
      if (v > best || (v == best && i < bi)) { best = v; bi = i; }
    }
    rv[tid] = best;
    ri[tid] = bi;
    __syncthreads();
    for (int s = 128; s; s >>= 1) {
      if (tid < s) {
        float ov = rv[tid + s];
        int oi = ri[tid + s];
        if (ov > rv[tid] || (ov == rv[tid] && oi < ri[tid])) {
          rv[tid] = ov;
          ri[tid] = oi;
        }
      }
      __syncthreads();
    }
    if (tid == 0) {
      mtop[bh * Uq + t] = ri[0];
      vals[ri[0]] = -INFINITY;
    }
    __syncthreads();
  }
}

// repl[b,h,l] = u if l == mtop[b,h,u] else -1 (table pre-filled with -1)
__global__ void scatter_repl(const int* __restrict__ mtop, int* __restrict__ repl) {
  int t = blockIdx.x * blockDim.x + threadIdx.x;
  if (t < Bq * Hq * Uq) {
    int bh = t / Uq;
    repl[(size_t)bh * Lq + mtop[t]] = t % Uq;
  }
}

// ---------------------------------------------------------------------------
// scores[bh][u][j] = (q[b,i0[u],h,:] . k[b,j,h,:]) / sqrt(D)
// ---------------------------------------------------------------------------
#define JT 256
#define JS 64

__global__ __launch_bounds__(256) void scores_kernel(
    const float* __restrict__ q, const float* __restrict__ k,
    const int* __restrict__ mtop, float* __restrict__ scg) {
  __shared__ float qs[Uq][DKq + 1];
  __shared__ float ks[JS][DKq + 1];
  __shared__ int i0s[Uq];
  int bh = blockIdx.y;
  int jt = blockIdx.x;
  int h = bh & (Hq - 1);
  int b = bh >> 3;
  int tid = threadIdx.x;
  if (tid < Uq) i0s[tid] = mtop[bh * Uq + tid];
  __syncthreads();
  for (int s = tid; s < Uq * 16; s += 256) {
    int u = s >> 4, qd = (s & 15) * 4;
    float4 t = *(const float4*)&q[((size_t)b * Lq + i0s[u]) * Dq + h * DKq + qd];
    qs[u][qd] = t.x; qs[u][qd + 1] = t.y; qs[u][qd + 2] = t.z; qs[u][qd + 3] = t.w;
  }
  int jp = tid & 31;
  int ug = tid >> 5;
  const float scale = 0.044194173824159216f;  // 1/sqrt(512)
  for (int sub = 0; sub < JT / JS; ++sub) {
    int jbase = jt * JT + sub * JS;
    __syncthreads();
    for (int s = tid; s < JS * 16; s += 256) {
      int j = s >> 4, qd = (s & 15) * 4;
      float4 t = *(const float4*)&k[((size_t)b * Lq + jbase + j) * Dq + h * DKq + qd];
      ks[j][qd] = t.x; ks[j][qd + 1] = t.y; ks[j][qd + 2] = t.z; ks[j][qd + 3] = t.w;
    }
    __syncthreads();
    float acc[3][2] = {};
    int j0 = jp * 2, j1 = j0 + 1;
#pragma unroll 8
    for (int d = 0; d < DKq; ++d) {
      float k0 = ks[j0][d], k1 = ks[j1][d];
#pragma unroll
      for (int uu = 0; uu < 3; ++uu) {
        float qv = qs[ug * 3 + uu][d];
        acc[uu][0] += qv * k0;
        acc[uu][1] += qv * k1;
      }
    }
#pragma unroll
    for (int uu = 0; uu < 3; ++uu) {
      int u = ug * 3 + uu;
      scg[((size_t)(bh * Uq + u)) * Lq + jbase + j0] = acc[uu][0] * scale;
      scg[((size_t)(bh * Uq + u)) * Lq + jbase + j1] = acc[uu][1] * scale;
    }
  }
}

// ---------------------------------------------------------------------------
// softmax over causal prefix + P@V; one block per (b,h,u)
// ---------------------------------------------------------------------------
__global__ __launch_bounds__(256) void softmax_pv(
    const float* __restrict__ scg, const float* __restrict__ v,
    const int* __restrict__ mtop, float* __restrict__ attnv) {
  __shared__ float es[Lq];
  __shared__ float red[4][DKq];
  __shared__ float rr[4];
  int blk = blockIdx.x;
  int bh = blk / Uq;
  int h = bh & (Hq - 1);
  int b = bh >> 3;
  int tid = threadIdx.x, wave = tid >> 6, lane = tid & 63;
  int i0 = mtop[blk];
  int n = i0 + 1;
  const float* row = &scg[(size_t)blk * Lq];

  float mx = -INFINITY;
  for (int j = tid; j < n; j += 256) mx = fmaxf(mx, row[j]);
#pragma unroll
  for (int off = 32; off; off >>= 1) mx = fmaxf(mx, __shfl_xor(mx, off, 64));
  if (lane == 0) rr[wave] = mx;
  __syncthreads();
  mx = fmaxf(fmaxf(rr[0], rr[1]), fmaxf(rr[2], rr[3]));
  __syncthreads();

  float sm = 0.f;
  for (int j = tid; j < n; j += 256) {
    float e = __expf(row[j] - mx);
    es[j] = e;
    sm += e;
  }
#pragma unroll
  for (int off = 32; off; off >>= 1) sm += __shfl_xor(sm, off, 64);
  if (lane == 0) rr[wave] = sm;
  __syncthreads();
  float inv = 1.0f / (rr[0] + rr[1] + rr[2] + rr[3]);

  float acc = 0.f;
  const float* vb = &v[(size_t)b * Lq * Dq + h * DKq + lane];
#pragma unroll 4
  for (int j = wave; j < n; j += 4) acc += es[j] * vb[(size_t)j * Dq];
  red[wave][lane] = acc;
  __syncthreads();
  if (wave == 0) {
    attnv[(size_t)blk * DKq + lane] =
        (red[0][lane] + red[1][lane] + red[2][lane] + red[3][lane]) * inv;
  }
}

// ---------------------------------------------------------------------------
// cumsum over L: 512-block tiled scan, float4 per thread, 16-row tiles
// ---------------------------------------------------------------------------
__global__ __launch_bounds__(128) void tile_sum(const float* __restrict__ v,
                                                float* __restrict__ tsum) {
  int blk = blockIdx.x;  // b*NTILE + tile
  int tile = blk & (NTILE - 1);
  int b = blk >> 7;
  int d4 = threadIdx.x;  // 0..127 (float4 column slice)
  float4 s = {0.f, 0.f, 0.f, 0.f};
  const float* base = &v[((size_t)b * Lq + tile * TSCAN) * Dq + d4 * 4];
#pragma unroll
  for (int r = 0; r < TSCAN; ++r) {
    float4 x = *(const float4*)&base[(size_t)r * Dq];
    s.x += x.x; s.y += x.y; s.z += x.z; s.w += x.w;
  }
  *(float4*)&tsum[((size_t)b * NTILE + tile) * Dq + d4 * 4] = s;
}

__global__ void tile_prefix(float* __restrict__ tsum) {
  int t = blockIdx.x * blockDim.x + threadIdx.x;  // B*D lanes
  if (t >= Bq * Dq) return;
  int b = t / Dq;
  int d = t % Dq;
  float run = 0.f;
  for (int i = 0; i < NTILE; ++i) {
    size_t off = ((size_t)b * NTILE + i) * Dq + d;
    float x = tsum[off];
    tsum[off] = run;
    run += x;
  }
}

__global__ __launch_bounds__(128) void build_context(
    const float* __restrict__ v, const float* __restrict__ tsum,
    const int* __restrict__ repl, const float* __restrict__ attnv,
    float* __restrict__ ctx) {
  int blk = blockIdx.x;  // b*NTILE + tile
  int tile = blk & (NTILE - 1);
  int b = blk >> 7;
  int d4 = threadIdx.x;          // float4 column slice
  int h = d4 >> 4;               // (d4*4)>>6
  float4 run = *(const float4*)&tsum[((size_t)b * NTILE + tile) * Dq + d4 * 4];
  const int* replb = &repl[(size_t)(b * Hq + h) * Lq + tile * TSCAN];
  const float* vb = &v[((size_t)b * Lq + tile * TSCAN) * Dq + d4 * 4];
  float* cb = &ctx[((size_t)b * Lq + tile * TSCAN) * Dq + d4 * 4];
  const float* ab = &attnv[(size_t)(b * Hq + h) * Uq * DKq + (d4 & 15) * 4];
#pragma unroll
  for (int r = 0; r < TSCAN; ++r) {
    float4 x = *(const float4*)&vb[(size_t)r * Dq];
    run.x += x.x; run.y += x.y; run.z += x.z; run.w += x.w;
    int u = replb[r];
    float4 val = run;
    if (u >= 0) val = *(const float4*)&ab[(size_t)u * DKq];
    *(float4*)&cb[(size_t)r * Dq] = val;
  }
}

// ---------------------------------------------------------------------------
extern "C" void kernel_launch(void* const* d_in, const int* in_sizes, int n_in,
                              void* d_out, int out_size, void* d_ws,
                              size_t ws_size, hipStream_t stream) {
  const float* queries = (const float*)d_in[0];
  const float* keys    = (const float*)d_in[1];
  const float* values  = (const float*)d_in[2];
  const int*   idxs    = (const int*)d_in[3];
  const float* Wq = (const float*)d_in[4];
  const float* bq = (const float*)d_in[5];
  const float* Wk = (const float*)d_in[6];
  const float* bk = (const float*)d_in[7];
  const float* Wv = (const float*)d_in[8];
  const float* bv = (const float*)d_in[9];
  const float* Wo = (const float*)d_in[10];
  const float* bo = (const float*)d_in[11];
  float* out = (float*)d_out;

  const size_t BLD = (size_t)Bq * Lq * Dq;  // 4,194,304
  char* w = (char*)d_ws;
  float* q    = (float*)w; w += BLD * 4;
  float* k    = (float*)w; w += BLD * 4;
  float* v    = (float*)w; w += BLD * 4;
  float* ctx  = (float*)w; w += BLD * 4;
  float* m    = (float*)w; w += (size_t)Bq * Hq * Lq * 4;
  float* attnv= (float*)w; w += (size_t)Bq * Hq * Uq * DKq * 4;
  float* tsum = (float*)w; w += (size_t)Bq * NTILE * Dq * 4;
  int* mtop   = (int*)w;   w += Bq * Hq * Uq * 4;
  int* repl   = (int*)w;   w += (size_t)Bq * Hq * Lq * 4;
  ushort_t* Ah = (ushort_t*)w; w += BLD * 2;   // reused across all 4 GEMMs
  ushort_t* Al = (ushort_t*)w; w += BLD * 2;
  const size_t WSZ = 512 * 512;
  ushort_t* Wqh = (ushort_t*)w; w += WSZ * 2;
  ushort_t* Wql = (ushort_t*)w; w += WSZ * 2;
  ushort_t* Wkh = (ushort_t*)w; w += WSZ * 2;
  ushort_t* Wkl = (ushort_t*)w; w += WSZ * 2;
  ushort_t* Wvh = (ushort_t*)w; w += WSZ * 2;
  ushort_t* Wvl = (ushort_t*)w; w += WSZ * 2;
  ushort_t* Woh = (ushort_t*)w; w += WSZ * 2;
  ushort_t* Wol = (ushort_t*)w; w += WSZ * 2;
  float* scg = ctx;  // scores alias ctx (consumed before ctx written)

  dim3 tgrid(16, 16);
  transpose_cast<<<tgrid, 256, 0, stream>>>(Wq, Wqh, Wql);
  transpose_cast<<<tgrid, 256, 0, stream>>>(Wk, Wkh, Wkl);
  transpose_cast<<<tgrid, 256, 0, stream>>>(Wv, Wvh, Wvl);
  transpose_cast<<<tgrid, 256, 0, stream>>>(Wo, Woh, Wol);

  dim3 ggrid(64, 8);  // M=8192/128, N=512/64
  const int CAST_B = (int)(BLD / 4 / 256);  // 4096 blocks

  // Q/K projections: split-bf16 (top-k-safe). V: plain bf16.
  cast_hilo<<<CAST_B, 256, 0, stream>>>(queries, Ah, Al, (int)(BLD / 4));
  gemm_split<<<ggrid, 256, 0, stream>>>(Ah, Al, Wqh, Wql, bq, q);
  cast_hilo<<<CAST_B, 256, 0, stream>>>(keys, Ah, Al, (int)(BLD / 4));
  gemm_split<<<ggrid, 256, 0, stream>>>(Ah, Al, Wkh, Wkl, bk, k);
  cast_hilo<<<CAST_B, 256, 0, stream>>>(values, Ah, Al, (int)(BLD / 4));
  gemm_bf16<<<ggrid, 256, 0, stream>>>(Ah, Wvh, bv, v);

  // sparsity metric + top-k
  compute_m<<<(Bq * Hq * Lq) / 16, 256, 0, stream>>>(q, k, idxs, m);
  topk_kernel<<<Bq * Hq, 256, 0, stream>>>(m, mtop);

  hipMemsetAsync(repl, 0xFF, (size_t)Bq * Hq * Lq * sizeof(int), stream);
  scatter_repl<<<3, 256, 0, stream>>>(mtop, repl);

  // attention on the top-24 rows
  {
    dim3 sgrid(Lq / JT, Bq * Hq);  // (8, 32)
    scores_kernel<<<sgrid, 256, 0, stream>>>(q, k, mtop, scg);
  }
  softmax_pv<<<Bq * Hq * Uq, 256, 0, stream>>>(scg, v, mtop, attnv);

  // cumsum context + scatter (512-block scan, 16-row tiles)
  tile_sum<<<Bq * NTILE, 128, 0, stream>>>(v, tsum);
  tile_prefix<<<(Bq * Dq + 255) / 256, 256, 0, stream>>>(tsum);
  build_context<<<Bq * NTILE, 128, 0, stream>>>(v, tsum, repl, attnv, ctx);

  // output projection (plain bf16)
  cast_hilo<<<CAST_B, 256, 0, stream>>>(ctx, Ah, Al, (int)(BLD / 4));
  gemm_bf16<<<ggrid, 256, 0, stream>>>(Ah, Woh, bo, out);
}

// Round 5
// 344.474 us; speedup vs baseline: 2.5855x; 1.0748x over previous
//
#include <hip/hip_runtime.h>
#include <hip/hip_bf16.h>
#include <math.h>

#define Bq 4
#define Lq 2048
#define Dq 512
#define Hq 8
#define DKq 64
#define Uq 24
#define TSCAN 16
#define NTILE (Lq / TSCAN)   // 128
#define JCH 256              // softmax j-chunk
#define NCH (Lq / JCH)       // 8

typedef unsigned short ushort_t;
typedef __attribute__((ext_vector_type(8))) short bfrag8;   // 8 bf16 (4 VGPRs)
typedef __attribute__((ext_vector_type(4))) float facc4;    // MFMA accumulator

__device__ inline ushort_t bf16_rne(float f) {
  unsigned u = __float_as_uint(f);
  u += 0x7FFF + ((u >> 16) & 1);
  return (ushort_t)(u >> 16);
}
__device__ inline float bf16f(ushort_t h) {
  return __uint_as_float(((unsigned)h) << 16);
}

// ---------------------------------------------------------------------------
// cast fp32 -> (bf16 hi, bf16 lo) elementwise; lo = rne(x - hi)
// ---------------------------------------------------------------------------
__global__ __launch_bounds__(256) void cast_hilo(
    const float* __restrict__ x, ushort_t* __restrict__ hi,
    ushort_t* __restrict__ lo, int n4) {
  int t = blockIdx.x * 256 + threadIdx.x;
  if (t >= n4) return;
  float4 v = *(const float4*)&x[(size_t)t * 4];
  ushort_t h0 = bf16_rne(v.x), h1 = bf16_rne(v.y), h2 = bf16_rne(v.z),
           h3 = bf16_rne(v.w);
  ushort4 hh = {h0, h1, h2, h3};
  ushort4 ll = {bf16_rne(v.x - bf16f(h0)), bf16_rne(v.y - bf16f(h1)),
                bf16_rne(v.z - bf16f(h2)), bf16_rne(v.w - bf16f(h3))};
  *(ushort4*)&hi[(size_t)t * 4] = hh;
  *(ushort4*)&lo[(size_t)t * 4] = ll;
}

// hi-only variant (for plain-bf16 GEMM inputs)
__global__ __launch_bounds__(256) void cast_hi(
    const float* __restrict__ x, ushort_t* __restrict__ hi, int n4) {
  int t = blockIdx.x * 256 + threadIdx.x;
  if (t >= n4) return;
  float4 v = *(const float4*)&x[(size_t)t * 4];
  ushort4 hh = {bf16_rne(v.x), bf16_rne(v.y), bf16_rne(v.z), bf16_rne(v.w)};
  *(ushort4*)&hi[(size_t)t * 4] = hh;
}

// ---------------------------------------------------------------------------
// W[512][512] fp32 -> Wt hi/lo bf16 [n][k] (transposed, 32x32 LDS tiles)
// ---------------------------------------------------------------------------
__global__ __launch_bounds__(256) void transpose_cast(
    const float* __restrict__ W, ushort_t* __restrict__ Th,
    ushort_t* __restrict__ Tl) {
  __shared__ float tile[32][33];
  int k0 = blockIdx.x * 32, n0 = blockIdx.y * 32;
  int tx = threadIdx.x & 31, ty = threadIdx.x >> 5;  // ty 0..7
  for (int r = ty; r < 32; r += 8)
    tile[tx][r] = W[(size_t)(k0 + r) * 512 + n0 + tx];
  __syncthreads();
  for (int r = ty; r < 32; r += 8) {
    float v = tile[r][tx];
    ushort_t h = bf16_rne(v);
    Th[(size_t)(n0 + r) * 512 + k0 + tx] = h;
    Tl[(size_t)(n0 + r) * 512 + k0 + tx] = bf16_rne(v - bf16f(h));
  }
}

// ---------------------------------------------------------------------------
// bf16 MFMA GEMM (hi only): C[8192x512] = A @ Bt^T + bias
// ---------------------------------------------------------------------------
__global__ __launch_bounds__(256) void gemm_bf16(
    const ushort_t* __restrict__ A, const ushort_t* __restrict__ Bt,
    const float* __restrict__ bias, float* __restrict__ C) {
  __shared__ ushort_t As[128][32];  // 8 KB  [m][k]
  __shared__ ushort_t Bs[64][32];   // 4 KB  [n][k]
  int bm = blockIdx.x, bn = blockIdx.y;
  int tid = threadIdx.x;
  int wave = tid >> 6, lane = tid & 63;
  int wm = (wave & 1) * 64, wn = (wave >> 1) * 32;
  int quad = lane >> 4, lm = lane & 15;
  facc4 acc[4][2] = {};

  for (int k0 = 0; k0 < 512; k0 += 32) {
#pragma unroll
    for (int p = 0; p < 2; ++p) {
      int s = p * 256 + tid;
      int row = s >> 2, kq = (s & 3) * 8;
      *(bfrag8*)&As[row][kq] =
          *(const bfrag8*)&A[(size_t)(bm * 128 + row) * 512 + k0 + kq];
    }
    {
      int row = tid >> 2, kq = (tid & 3) * 8;
      *(bfrag8*)&Bs[row][kq] =
          *(const bfrag8*)&Bt[(size_t)(bn * 64 + row) * 512 + k0 + kq];
    }
    __syncthreads();
    bfrag8 af[4], bf[2];
#pragma unroll
    for (int mt = 0; mt < 4; ++mt)
      af[mt] = *(bfrag8*)&As[wm + mt * 16 + lm][quad * 8];
#pragma unroll
    for (int nt = 0; nt < 2; ++nt)
      bf[nt] = *(bfrag8*)&Bs[wn + nt * 16 + lm][quad * 8];
#pragma unroll
    for (int mt = 0; mt < 4; ++mt)
#pragma unroll
      for (int nt = 0; nt < 2; ++nt)
        acc[mt][nt] = __builtin_amdgcn_mfma_f32_16x16x32_bf16(
            af[mt], bf[nt], acc[mt][nt], 0, 0, 0);
    __syncthreads();
  }
#pragma unroll
  for (int mt = 0; mt < 4; ++mt)
#pragma unroll
    for (int nt = 0; nt < 2; ++nt) {
      int col = bn * 64 + wn + nt * 16 + lm;
      float bv = bias[col];
#pragma unroll
      for (int r = 0; r < 4; ++r) {
        int row = bm * 128 + wm + mt * 16 + quad * 4 + r;
        C[(size_t)row * 512 + col] = acc[mt][nt][r] + bv;
      }
    }
}

// ---------------------------------------------------------------------------
// split-bf16 MFMA GEMM: C = (Ah+Al) @ (Bh+Bl)^T + bias, skipping Al*Bl.
// ---------------------------------------------------------------------------
__global__ __launch_bounds__(256) void gemm_split(
    const ushort_t* __restrict__ Ah, const ushort_t* __restrict__ Al,
    const ushort_t* __restrict__ Bth, const ushort_t* __restrict__ Btl,
    const float* __restrict__ bias, float* __restrict__ C) {
  __shared__ ushort_t Ash[128][32], Asl[128][32];  // 16 KB
  __shared__ ushort_t Bsh[64][32], Bsl[64][32];    // 8 KB
  int bm = blockIdx.x, bn = blockIdx.y;
  int tid = threadIdx.x;
  int wave = tid >> 6, lane = tid & 63;
  int wm = (wave & 1) * 64, wn = (wave >> 1) * 32;
  int quad = lane >> 4, lm = lane & 15;
  facc4 acc[4][2] = {};

  for (int k0 = 0; k0 < 512; k0 += 32) {
#pragma unroll
    for (int p = 0; p < 2; ++p) {
      int s = p * 256 + tid;
      int row = s >> 2, kq = (s & 3) * 8;
      size_t g = (size_t)(bm * 128 + row) * 512 + k0 + kq;
      *(bfrag8*)&Ash[row][kq] = *(const bfrag8*)&Ah[g];
      *(bfrag8*)&Asl[row][kq] = *(const bfrag8*)&Al[g];
    }
    {
      int row = tid >> 2, kq = (tid & 3) * 8;
      size_t g = (size_t)(bn * 64 + row) * 512 + k0 + kq;
      *(bfrag8*)&Bsh[row][kq] = *(const bfrag8*)&Bth[g];
      *(bfrag8*)&Bsl[row][kq] = *(const bfrag8*)&Btl[g];
    }
    __syncthreads();
    bfrag8 afh[4], afl[4], bfh[2], bfl[2];
#pragma unroll
    for (int mt = 0; mt < 4; ++mt) {
      afh[mt] = *(bfrag8*)&Ash[wm + mt * 16 + lm][quad * 8];
      afl[mt] = *(bfrag8*)&Asl[wm + mt * 16 + lm][quad * 8];
    }
#pragma unroll
    for (int nt = 0; nt < 2; ++nt) {
      bfh[nt] = *(bfrag8*)&Bsh[wn + nt * 16 + lm][quad * 8];
      bfl[nt] = *(bfrag8*)&Bsl[wn + nt * 16 + lm][quad * 8];
    }
#pragma unroll
    for (int mt = 0; mt < 4; ++mt)
#pragma unroll
      for (int nt = 0; nt < 2; ++nt) {
        facc4 a = acc[mt][nt];
        a = __builtin_amdgcn_mfma_f32_16x16x32_bf16(afh[mt], bfh[nt], a, 0, 0, 0);
        a = __builtin_amdgcn_mfma_f32_16x16x32_bf16(afl[mt], bfh[nt], a, 0, 0, 0);
        a = __builtin_amdgcn_mfma_f32_16x16x32_bf16(afh[mt], bfl[nt], a, 0, 0, 0);
        acc[mt][nt] = a;
      }
    __syncthreads();
  }
#pragma unroll
  for (int mt = 0; mt < 4; ++mt)
#pragma unroll
    for (int nt = 0; nt < 2; ++nt) {
      int col = bn * 64 + wn + nt * 16 + lm;
      float bv = bias[col];
#pragma unroll
      for (int r = 0; r < 4; ++r) {
        int row = bm * 128 + wm + mt * 16 + quad * 4 + r;
        C[(size_t)row * 512 + col] = acc[mt][nt][r] + bv;
      }
    }
}

// ---------------------------------------------------------------------------
// m[b,h,l] = max_s(q.k_sample) - sum_s(q.k_sample)/L
// ---------------------------------------------------------------------------
__global__ __launch_bounds__(256) void compute_m(
    const float* __restrict__ q, const float* __restrict__ k,
    const int* __restrict__ idxs, float* __restrict__ m) {
  int wave = threadIdx.x >> 6, lane = threadIdx.x & 63;
  int lq = lane >> 4, dq = lane & 15;
  int slot = (blockIdx.x * 4 + wave) * 4 + lq;  // (b,h,l) flat
  int l = slot & (Lq - 1);
  int bh = slot >> 11;
  int h = bh & (Hq - 1), b = bh >> 3;
  float4 qv = *(const float4*)&q[((size_t)b * Lq + l) * Dq + h * DKq + dq * 4];
  const float* kb = &k[(size_t)b * Lq * Dq + h * DKq + dq * 4];
  const int* ib = &idxs[l * Uq];
  float mx = -INFINITY, sm = 0.f;
#pragma unroll
  for (int s = 0; s < Uq; ++s) {
    int j = ib[s];
    float4 kv = *(const float4*)&kb[(size_t)j * Dq];
    float p = qv.x * kv.x + qv.y * kv.y + qv.z * kv.z + qv.w * kv.w;
    p += __shfl_xor(p, 1, 64);
    p += __shfl_xor(p, 2, 64);
    p += __shfl_xor(p, 4, 64);
    p += __shfl_xor(p, 8, 64);
    mx = fmaxf(mx, p);
    sm += p;
  }
  if (dq == 0) m[slot] = mx - sm * (1.0f / Lq);
}

// ---------------------------------------------------------------------------
// top-24 per (b,h): iterative argmax, tie-break smaller index (lax.top_k)
// ---------------------------------------------------------------------------
__global__ __launch_bounds__(256) void topk_kernel(
    const float* __restrict__ m, int* __restrict__ mtop) {
  __shared__ float vals[Lq];
  __shared__ float rv[256];
  __shared__ int ri[256];
  int bh = blockIdx.x;
  int tid = threadIdx.x;
  for (int i = tid; i < Lq; i += 256) vals[i] = m[(size_t)bh * Lq + i];
  __syncthreads();
  for (int t = 0; t < Uq; ++t) {
    float best = -INFINITY;
    int bi = Lq;
    for (int i = tid; i < Lq; i += 256) {
      float v = vals[i];
      if (v > best || (v == best && i < bi)) { best = v; bi = i; }
    }
    rv[tid] = best;
    ri[tid] = bi;
    __syncthreads();
    for (int s = 128; s; s >>= 1) {
      if (tid < s) {
        float ov = rv[tid + s];
        int oi = ri[tid + s];
        if (ov > rv[tid] || (ov == rv[tid] && oi < ri[tid])) {
          rv[tid] = ov;
          ri[tid] = oi;
        }
      }
      __syncthreads();
    }
    if (tid == 0) {
      mtop[bh * Uq + t] = ri[0];
      vals[ri[0]] = -INFINITY;
    }
    __syncthreads();
  }
}

// repl[b,h,l] = u if l == mtop[b,h,u] else -1 (table pre-filled with -1)
__global__ void scatter_repl(const int* __restrict__ mtop, int* __restrict__ repl) {
  int t = blockIdx.x * blockDim.x + threadIdx.x;
  if (t < Bq * Hq * Uq) {
    int bh = t / Uq;
    repl[(size_t)bh * Lq + mtop[t]] = t % Uq;
  }
}

// ---------------------------------------------------------------------------
// scores[bh][u][j] = (q[b,i0[u],h,:] . k[b,j,h,:]) / sqrt(D)
// ---------------------------------------------------------------------------
#define JT 256
#define JS 64

__global__ __launch_bounds__(256) void scores_kernel(
    const float* __restrict__ q, const float* __restrict__ k,
    const int* __restrict__ mtop, float* __restrict__ scg) {
  __shared__ float qs[Uq][DKq + 1];
  __shared__ float ks[JS][DKq + 1];
  __shared__ int i0s[Uq];
  int bh = blockIdx.y;
  int jt = blockIdx.x;
  int h = bh & (Hq - 1);
  int b = bh >> 3;
  int tid = threadIdx.x;
  if (tid < Uq) i0s[tid] = mtop[bh * Uq + tid];
  __syncthreads();
  for (int s = tid; s < Uq * 16; s += 256) {
    int u = s >> 4, qd = (s & 15) * 4;
    float4 t = *(const float4*)&q[((size_t)b * Lq + i0s[u]) * Dq + h * DKq + qd];
    qs[u][qd] = t.x; qs[u][qd + 1] = t.y; qs[u][qd + 2] = t.z; qs[u][qd + 3] = t.w;
  }
  int jp = tid & 31;
  int ug = tid >> 5;
  const float scale = 0.044194173824159216f;  // 1/sqrt(512)
  for (int sub = 0; sub < JT / JS; ++sub) {
    int jbase = jt * JT + sub * JS;
    __syncthreads();
    for (int s = tid; s < JS * 16; s += 256) {
      int j = s >> 4, qd = (s & 15) * 4;
      float4 t = *(const float4*)&k[((size_t)b * Lq + jbase + j) * Dq + h * DKq + qd];
      ks[j][qd] = t.x; ks[j][qd + 1] = t.y; ks[j][qd + 2] = t.z; ks[j][qd + 3] = t.w;
    }
    __syncthreads();
    float acc[3][2] = {};
    int j0 = jp * 2, j1 = j0 + 1;
#pragma unroll 8
    for (int d = 0; d < DKq; ++d) {
      float k0 = ks[j0][d], k1 = ks[j1][d];
#pragma unroll
      for (int uu = 0; uu < 3; ++uu) {
        float qv = qs[ug * 3 + uu][d];
        acc[uu][0] += qv * k0;
        acc[uu][1] += qv * k1;
      }
    }
#pragma unroll
    for (int uu = 0; uu < 3; ++uu) {
      int u = ug * 3 + uu;
      scg[((size_t)(bh * Uq + u)) * Lq + jbase + j0] = acc[uu][0] * scale;
      scg[((size_t)(bh * Uq + u)) * Lq + jbase + j1] = acc[uu][1] * scale;
    }
  }
}

// ---------------------------------------------------------------------------
// softmax+PV, split over j-chunks of 256 for TLP.
// partial: grid (NCH, B*H*U); per chunk local max/sum/PV partials.
// combine: one wave per (b,h,u) merges <=8 chunks.
// ---------------------------------------------------------------------------
__global__ __launch_bounds__(256) void softmax_pv_partial(
    const float* __restrict__ scg, const float* __restrict__ v,
    const int* __restrict__ mtop, float* __restrict__ pmax,
    float* __restrict__ psum, float* __restrict__ pvp) {
  int blk = blockIdx.y;  // bh*U + u
  int jc = blockIdx.x;
  int bh = blk / Uq;
  int h = bh & (Hq - 1);
  int b = bh >> 3;
  int n = mtop[blk] + 1;   // causal bound
  int j0 = jc * JCH;
  if (j0 >= n) return;
  int cnt = min(JCH, n - j0);
  int tid = threadIdx.x, wave = tid >> 6, lane = tid & 63;
  __shared__ float es[JCH];
  __shared__ float red[4][DKq];
  __shared__ float rr[4];

  const float* row = &scg[(size_t)blk * Lq + j0];
  float mx = (tid < cnt) ? row[tid] : -INFINITY;
#pragma unroll
  for (int off = 32; off; off >>= 1) mx = fmaxf(mx, __shfl_xor(mx, off, 64));
  if (lane == 0) rr[wave] = mx;
  __syncthreads();
  mx = fmaxf(fmaxf(rr[0], rr[1]), fmaxf(rr[2], rr[3]));
  __syncthreads();

  float e = (tid < cnt) ? __expf(row[tid] - mx) : 0.f;
  es[tid] = e;
  float sm = e;
#pragma unroll
  for (int off = 32; off; off >>= 1) sm += __shfl_xor(sm, off, 64);
  if (lane == 0) rr[wave] = sm;
  __syncthreads();

  // PV: wave w covers j in [w*64, w*64+64); es is 0 past cnt, v in-bounds.
  float acc = 0.f;
  const float* vb = &v[((size_t)b * Lq + j0) * Dq + h * DKq + lane];
  int jlo = wave * 64;
  int jhi = min(jlo + 64, cnt);
#pragma unroll 4
  for (int j = jlo; j < jhi; ++j) acc += es[j] * vb[(size_t)j * Dq];
  red[wave][lane] = acc;
  __syncthreads();
  if (wave == 0) {
    if (lane == 0) {
      pmax[blk * NCH + jc] = mx;
      psum[blk * NCH + jc] = rr[0] + rr[1] + rr[2] + rr[3];
    }
    pvp[((size_t)blk * NCH + jc) * DKq + lane] =
        red[0][lane] + red[1][lane] + red[2][lane] + red[3][lane];
  }
}

__global__ __launch_bounds__(256) void softmax_pv_combine(
    const float* __restrict__ pmax, const float* __restrict__ psum,
    const float* __restrict__ pvp, const int* __restrict__ mtop,
    float* __restrict__ attnv) {
  int blk = blockIdx.x * 4 + (threadIdx.x >> 6);  // bh*U + u
  int lane = threadIdx.x & 63;
  int n = mtop[blk] + 1;
  int nc = (n + JCH - 1) / JCH;
  float gmax = -INFINITY;
  for (int c = 0; c < nc; ++c) gmax = fmaxf(gmax, pmax[blk * NCH + c]);
  float tot = 0.f, acc = 0.f;
  for (int c = 0; c < nc; ++c) {
    float w = __expf(pmax[blk * NCH + c] - gmax);
    tot += psum[blk * NCH + c] * w;
    acc += pvp[((size_t)blk * NCH + c) * DKq + lane] * w;
  }
  attnv[(size_t)blk * DKq + lane] = acc / tot;
}

// ---------------------------------------------------------------------------
// cumsum over L: 512-block tiled scan, float4 per thread, 16-row tiles
// ---------------------------------------------------------------------------
__global__ __launch_bounds__(128) void tile_sum(const float* __restrict__ v,
                                                float* __restrict__ tsum) {
  int blk = blockIdx.x;  // b*NTILE + tile
  int tile = blk & (NTILE - 1);
  int b = blk >> 7;
  int d4 = threadIdx.x;  // 0..127 (float4 column slice)
  float4 s = {0.f, 0.f, 0.f, 0.f};
  const float* base = &v[((size_t)b * Lq + tile * TSCAN) * Dq + d4 * 4];
#pragma unroll
  for (int r = 0; r < TSCAN; ++r) {
    float4 x = *(const float4*)&base[(size_t)r * Dq];
    s.x += x.x; s.y += x.y; s.z += x.z; s.w += x.w;
  }
  *(float4*)&tsum[((size_t)b * NTILE + tile) * Dq + d4 * 4] = s;
}

__global__ void tile_prefix(float* __restrict__ tsum) {
  int t = blockIdx.x * blockDim.x + threadIdx.x;  // B*D lanes
  if (t >= Bq * Dq) return;
  int b = t / Dq;
  int d = t % Dq;
  float run = 0.f;
  for (int i = 0; i < NTILE; ++i) {
    size_t off = ((size_t)b * NTILE + i) * Dq + d;
    float x = tsum[off];
    tsum[off] = run;
    run += x;
  }
}

__global__ __launch_bounds__(128) void build_context(
    const float* __restrict__ v, const float* __restrict__ tsum,
    const int* __restrict__ repl, const float* __restrict__ attnv,
    float* __restrict__ ctx) {
  int blk = blockIdx.x;  // b*NTILE + tile
  int tile = blk & (NTILE - 1);
  int b = blk >> 7;
  int d4 = threadIdx.x;          // float4 column slice
  int h = d4 >> 4;               // (d4*4)>>6
  float4 run = *(const float4*)&tsum[((size_t)b * NTILE + tile) * Dq + d4 * 4];
  const int* replb = &repl[(size_t)(b * Hq + h) * Lq + tile * TSCAN];
  const float* vb = &v[((size_t)b * Lq + tile * TSCAN) * Dq + d4 * 4];
  float* cb = &ctx[((size_t)b * Lq + tile * TSCAN) * Dq + d4 * 4];
  const float* ab = &attnv[(size_t)(b * Hq + h) * Uq * DKq + (d4 & 15) * 4];
#pragma unroll
  for (int r = 0; r < TSCAN; ++r) {
    float4 x = *(const float4*)&vb[(size_t)r * Dq];
    run.x += x.x; run.y += x.y; run.z += x.z; run.w += x.w;
    int u = replb[r];
    float4 val = run;
    if (u >= 0) val = *(const float4*)&ab[(size_t)u * DKq];
    *(float4*)&cb[(size_t)r * Dq] = val;
  }
}

// ---------------------------------------------------------------------------
extern "C" void kernel_launch(void* const* d_in, const int* in_sizes, int n_in,
                              void* d_out, int out_size, void* d_ws,
                              size_t ws_size, hipStream_t stream) {
  const float* queries = (const float*)d_in[0];
  const float* keys    = (const float*)d_in[1];
  const float* values  = (const float*)d_in[2];
  const int*   idxs    = (const int*)d_in[3];
  const float* Wq = (const float*)d_in[4];
  const float* bq = (const float*)d_in[5];
  const float* Wk = (const float*)d_in[6];
  const float* bk = (const float*)d_in[7];
  const float* Wv = (const float*)d_in[8];
  const float* bv = (const float*)d_in[9];
  const float* Wo = (const float*)d_in[10];
  const float* bo = (const float*)d_in[11];
  float* out = (float*)d_out;

  const size_t BLD = (size_t)Bq * Lq * Dq;  // 4,194,304
  char* w = (char*)d_ws;
  float* q    = (float*)w; w += BLD * 4;
  float* k    = (float*)w; w += BLD * 4;
  float* v    = (float*)w; w += BLD * 4;
  float* ctx  = (float*)w; w += BLD * 4;
  float* m    = (float*)w; w += (size_t)Bq * Hq * Lq * 4;
  float* attnv= (float*)w; w += (size_t)Bq * Hq * Uq * DKq * 4;
  float* tsum = (float*)w; w += (size_t)Bq * NTILE * Dq * 4;
  int* mtop   = (int*)w;   w += Bq * Hq * Uq * 4;
  int* repl   = (int*)w;   w += (size_t)Bq * Hq * Lq * 4;
  float* pmax = (float*)w; w += (size_t)Bq * Hq * Uq * NCH * 4;
  float* psum = (float*)w; w += (size_t)Bq * Hq * Uq * NCH * 4;
  float* pvp  = (float*)w; w += (size_t)Bq * Hq * Uq * NCH * DKq * 4;
  ushort_t* Ah = (ushort_t*)w; w += BLD * 2;   // reused across all 4 GEMMs
  ushort_t* Al = (ushort_t*)w; w += BLD * 2;
  const size_t WSZ = 512 * 512;
  ushort_t* Wqh = (ushort_t*)w; w += WSZ * 2;
  ushort_t* Wql = (ushort_t*)w; w += WSZ * 2;
  ushort_t* Wkh = (ushort_t*)w; w += WSZ * 2;
  ushort_t* Wkl = (ushort_t*)w; w += WSZ * 2;
  ushort_t* Wvh = (ushort_t*)w; w += WSZ * 2;
  ushort_t* Wvl = (ushort_t*)w; w += WSZ * 2;
  ushort_t* Woh = (ushort_t*)w; w += WSZ * 2;
  ushort_t* Wol = (ushort_t*)w; w += WSZ * 2;
  float* scg = ctx;  // scores alias ctx (consumed before ctx written)

  dim3 tgrid(16, 16);
  transpose_cast<<<tgrid, 256, 0, stream>>>(Wq, Wqh, Wql);
  transpose_cast<<<tgrid, 256, 0, stream>>>(Wk, Wkh, Wkl);
  transpose_cast<<<tgrid, 256, 0, stream>>>(Wv, Wvh, Wvl);
  transpose_cast<<<tgrid, 256, 0, stream>>>(Wo, Woh, Wol);

  dim3 ggrid(64, 8);  // M=8192/128, N=512/64
  const int CAST_B = (int)(BLD / 4 / 256);  // 4096 blocks

  // Q/K projections: split-bf16 (top-k-safe). V: plain bf16.
  cast_hilo<<<CAST_B, 256, 0, stream>>>(queries, Ah, Al, (int)(BLD / 4));
  gemm_split<<<ggrid, 256, 0, stream>>>(Ah, Al, Wqh, Wql, bq, q);
  cast_hilo<<<CAST_B, 256, 0, stream>>>(keys, Ah, Al, (int)(BLD / 4));
  gemm_split<<<ggrid, 256, 0, stream>>>(Ah, Al, Wkh, Wkl, bk, k);
  cast_hi<<<CAST_B, 256, 0, stream>>>(values, Ah, (int)(BLD / 4));
  gemm_bf16<<<ggrid, 256, 0, stream>>>(Ah, Wvh, bv, v);

  // sparsity metric + top-k
  compute_m<<<(Bq * Hq * Lq) / 16, 256, 0, stream>>>(q, k, idxs, m);
  topk_kernel<<<Bq * Hq, 256, 0, stream>>>(m, mtop);

  hipMemsetAsync(repl, 0xFF, (size_t)Bq * Hq * Lq * sizeof(int), stream);
  scatter_repl<<<3, 256, 0, stream>>>(mtop, repl);

  // attention on the top-24 rows
  {
    dim3 sgrid(Lq / JT, Bq * Hq);  // (8, 32)
    scores_kernel<<<sgrid, 256, 0, stream>>>(q, k, mtop, scg);
  }
  {
    dim3 pgrid(NCH, Bq * Hq * Uq);  // (8, 768)
    softmax_pv_partial<<<pgrid, 256, 0, stream>>>(scg, v, mtop, pmax, psum, pvp);
    softmax_pv_combine<<<Bq * Hq * Uq / 4, 256, 0, stream>>>(pmax, psum, pvp,
                                                             mtop, attnv);
  }

  // cumsum context + scatter (512-block scan, 16-row tiles)
  tile_sum<<<Bq * NTILE, 128, 0, stream>>>(v, tsum);
  tile_prefix<<<(Bq * Dq + 255) / 256, 256, 0, stream>>>(tsum);
  build_context<<<Bq * NTILE, 128, 0, stream>>>(v, tsum, repl, attnv, ctx);

  // output projection (plain bf16)
  cast_hi<<<CAST_B, 256, 0, stream>>>(ctx, Ah, (int)(BLD / 4));
  gemm_bf16<<<ggrid, 256, 0, stream>>>(Ah, Woh, bo, out);
}

// Round 6
// 313.990 us; speedup vs baseline: 2.8366x; 1.0971x over previous
//
#include <hip/hip_runtime.h>
#include <hip/hip_bf16.h>
#include <math.h>

#define Bq 4
#define Lq 2048
#define Dq 512
#define Hq 8
#define DKq 64
#define Uq 24
#define TSCAN 16
#define NTILE (Lq / TSCAN)   // 128
#define JCH 256              // softmax j-chunk
#define NCH (Lq / JCH)       // 8
#define TKCH 8               // top-k chunks per bh

typedef unsigned short ushort_t;
typedef unsigned long long u64;
typedef __attribute__((ext_vector_type(8))) short bfrag8;   // 8 bf16 (4 VGPRs)
typedef __attribute__((ext_vector_type(4))) float facc4;    // MFMA accumulator

__device__ inline ushort_t bf16_rne(float f) {
  unsigned u = __float_as_uint(f);
  u += 0x7FFF + ((u >> 16) & 1);
  return (ushort_t)(u >> 16);
}
__device__ inline float bf16f(ushort_t h) {
  return __uint_as_float(((unsigned)h) << 16);
}
// monotone float -> uint map (no NaNs in inputs)
__device__ inline unsigned fkey(float f) {
  unsigned u = __float_as_uint(f);
  return (u & 0x80000000u) ? ~u : (u | 0x80000000u);
}

// ---------------------------------------------------------------------------
// cast fp32 -> (bf16 hi, bf16 lo) elementwise; lo = rne(x - hi)
// ---------------------------------------------------------------------------
__global__ __launch_bounds__(256) void cast_hilo(
    const float* __restrict__ x, ushort_t* __restrict__ hi,
    ushort_t* __restrict__ lo, int n4) {
  int t = blockIdx.x * 256 + threadIdx.x;
  if (t >= n4) return;
  float4 v = *(const float4*)&x[(size_t)t * 4];
  ushort_t h0 = bf16_rne(v.x), h1 = bf16_rne(v.y), h2 = bf16_rne(v.z),
           h3 = bf16_rne(v.w);
  ushort4 hh = {h0, h1, h2, h3};
  ushort4 ll = {bf16_rne(v.x - bf16f(h0)), bf16_rne(v.y - bf16f(h1)),
                bf16_rne(v.z - bf16f(h2)), bf16_rne(v.w - bf16f(h3))};
  *(ushort4*)&hi[(size_t)t * 4] = hh;
  *(ushort4*)&lo[(size_t)t * 4] = ll;
}

// hi-only variant (for plain-bf16 GEMM inputs)
__global__ __launch_bounds__(256) void cast_hi(
    const float* __restrict__ x, ushort_t* __restrict__ hi, int n4) {
  int t = blockIdx.x * 256 + threadIdx.x;
  if (t >= n4) return;
  float4 v = *(const float4*)&x[(size_t)t * 4];
  ushort4 hh = {bf16_rne(v.x), bf16_rne(v.y), bf16_rne(v.z), bf16_rne(v.w)};
  *(ushort4*)&hi[(size_t)t * 4] = hh;
}

// ---------------------------------------------------------------------------
// W[512][512] fp32 -> Wt hi/lo bf16 [n][k] (transposed, 32x32 LDS tiles)
// ---------------------------------------------------------------------------
__global__ __launch_bounds__(256) void transpose_cast(
    const float* __restrict__ W, ushort_t* __restrict__ Th,
    ushort_t* __restrict__ Tl) {
  __shared__ float tile[32][33];
  int k0 = blockIdx.x * 32, n0 = blockIdx.y * 32;
  int tx = threadIdx.x & 31, ty = threadIdx.x >> 5;  // ty 0..7
  for (int r = ty; r < 32; r += 8)
    tile[tx][r] = W[(size_t)(k0 + r) * 512 + n0 + tx];
  __syncthreads();
  for (int r = ty; r < 32; r += 8) {
    float v = tile[r][tx];
    ushort_t h = bf16_rne(v);
    Th[(size_t)(n0 + r) * 512 + k0 + tx] = h;
    Tl[(size_t)(n0 + r) * 512 + k0 + tx] = bf16_rne(v - bf16f(h));
  }
}

// ---------------------------------------------------------------------------
// bf16 MFMA GEMM (hi only): C[8192x512] = A @ Bt^T + bias
// ---------------------------------------------------------------------------
__global__ __launch_bounds__(256) void gemm_bf16(
    const ushort_t* __restrict__ A, const ushort_t* __restrict__ Bt,
    const float* __restrict__ bias, float* __restrict__ C) {
  __shared__ ushort_t As[128][32];  // 8 KB  [m][k]
  __shared__ ushort_t Bs[64][32];   // 4 KB  [n][k]
  int bm = blockIdx.x, bn = blockIdx.y;
  int tid = threadIdx.x;
  int wave = tid >> 6, lane = tid & 63;
  int wm = (wave & 1) * 64, wn = (wave >> 1) * 32;
  int quad = lane >> 4, lm = lane & 15;
  facc4 acc[4][2] = {};

  for (int k0 = 0; k0 < 512; k0 += 32) {
#pragma unroll
    for (int p = 0; p < 2; ++p) {
      int s = p * 256 + tid;
      int row = s >> 2, kq = (s & 3) * 8;
      *(bfrag8*)&As[row][kq] =
          *(const bfrag8*)&A[(size_t)(bm * 128 + row) * 512 + k0 + kq];
    }
    {
      int row = tid >> 2, kq = (tid & 3) * 8;
      *(bfrag8*)&Bs[row][kq] =
          *(const bfrag8*)&Bt[(size_t)(bn * 64 + row) * 512 + k0 + kq];
    }
    __syncthreads();
    bfrag8 af[4], bf[2];
#pragma unroll
    for (int mt = 0; mt < 4; ++mt)
      af[mt] = *(bfrag8*)&As[wm + mt * 16 + lm][quad * 8];
#pragma unroll
    for (int nt = 0; nt < 2; ++nt)
      bf[nt] = *(bfrag8*)&Bs[wn + nt * 16 + lm][quad * 8];
#pragma unroll
    for (int mt = 0; mt < 4; ++mt)
#pragma unroll
      for (int nt = 0; nt < 2; ++nt)
        acc[mt][nt] = __builtin_amdgcn_mfma_f32_16x16x32_bf16(
            af[mt], bf[nt], acc[mt][nt], 0, 0, 0);
    __syncthreads();
  }
#pragma unroll
  for (int mt = 0; mt < 4; ++mt)
#pragma unroll
    for (int nt = 0; nt < 2; ++nt) {
      int col = bn * 64 + wn + nt * 16 + lm;
      float bv = bias[col];
#pragma unroll
      for (int r = 0; r < 4; ++r) {
        int row = bm * 128 + wm + mt * 16 + quad * 4 + r;
        C[(size_t)row * 512 + col] = acc[mt][nt][r] + bv;
      }
    }
}

// ---------------------------------------------------------------------------
// split-bf16 MFMA GEMM: C = (Ah+Al) @ (Bh+Bl)^T + bias, skipping Al*Bl.
// ---------------------------------------------------------------------------
__global__ __launch_bounds__(256) void gemm_split(
    const ushort_t* __restrict__ Ah, const ushort_t* __restrict__ Al,
    const ushort_t* __restrict__ Bth, const ushort_t* __restrict__ Btl,
    const float* __restrict__ bias, float* __restrict__ C) {
  __shared__ ushort_t Ash[128][32], Asl[128][32];  // 16 KB
  __shared__ ushort_t Bsh[64][32], Bsl[64][32];    // 8 KB
  int bm = blockIdx.x, bn = blockIdx.y;
  int tid = threadIdx.x;
  int wave = tid >> 6, lane = tid & 63;
  int wm = (wave & 1) * 64, wn = (wave >> 1) * 32;
  int quad = lane >> 4, lm = lane & 15;
  facc4 acc[4][2] = {};

  for (int k0 = 0; k0 < 512; k0 += 32) {
#pragma unroll
    for (int p = 0; p < 2; ++p) {
      int s = p * 256 + tid;
      int row = s >> 2, kq = (s & 3) * 8;
      size_t g = (size_t)(bm * 128 + row) * 512 + k0 + kq;
      *(bfrag8*)&Ash[row][kq] = *(const bfrag8*)&Ah[g];
      *(bfrag8*)&Asl[row][kq] = *(const bfrag8*)&Al[g];
    }
    {
      int row = tid >> 2, kq = (tid & 3) * 8;
      size_t g = (size_t)(bn * 64 + row) * 512 + k0 + kq;
      *(bfrag8*)&Bsh[row][kq] = *(const bfrag8*)&Bth[g];
      *(bfrag8*)&Bsl[row][kq] = *(const bfrag8*)&Btl[g];
    }
    __syncthreads();
    bfrag8 afh[4], afl[4], bfh[2], bfl[2];
#pragma unroll
    for (int mt = 0; mt < 4; ++mt) {
      afh[mt] = *(bfrag8*)&Ash[wm + mt * 16 + lm][quad * 8];
      afl[mt] = *(bfrag8*)&Asl[wm + mt * 16 + lm][quad * 8];
    }
#pragma unroll
    for (int nt = 0; nt < 2; ++nt) {
      bfh[nt] = *(bfrag8*)&Bsh[wn + nt * 16 + lm][quad * 8];
      bfl[nt] = *(bfrag8*)&Bsl[wn + nt * 16 + lm][quad * 8];
    }
#pragma unroll
    for (int mt = 0; mt < 4; ++mt)
#pragma unroll
      for (int nt = 0; nt < 2; ++nt) {
        facc4 a = acc[mt][nt];
        a = __builtin_amdgcn_mfma_f32_16x16x32_bf16(afh[mt], bfh[nt], a, 0, 0, 0);
        a = __builtin_amdgcn_mfma_f32_16x16x32_bf16(afl[mt], bfh[nt], a, 0, 0, 0);
        a = __builtin_amdgcn_mfma_f32_16x16x32_bf16(afh[mt], bfl[nt], a, 0, 0, 0);
        acc[mt][nt] = a;
      }
    __syncthreads();
  }
#pragma unroll
  for (int mt = 0; mt < 4; ++mt)
#pragma unroll
    for (int nt = 0; nt < 2; ++nt) {
      int col = bn * 64 + wn + nt * 16 + lm;
      float bv = bias[col];
#pragma unroll
      for (int r = 0; r < 4; ++r) {
        int row = bm * 128 + wm + mt * 16 + quad * 4 + r;
        C[(size_t)row * 512 + col] = acc[mt][nt][r] + bv;
      }
    }
}

// ---------------------------------------------------------------------------
// m[b,h,l] = max_s(q.k_sample) - sum_s(q.k_sample)/L
// ---------------------------------------------------------------------------
__global__ __launch_bounds__(256) void compute_m(
    const float* __restrict__ q, const float* __restrict__ k,
    const int* __restrict__ idxs, float* __restrict__ m) {
  int wave = threadIdx.x >> 6, lane = threadIdx.x & 63;
  int lq = lane >> 4, dq = lane & 15;
  int slot = (blockIdx.x * 4 + wave) * 4 + lq;  // (b,h,l) flat
  int l = slot & (Lq - 1);
  int bh = slot >> 11;
  int h = bh & (Hq - 1), b = bh >> 3;
  float4 qv = *(const float4*)&q[((size_t)b * Lq + l) * Dq + h * DKq + dq * 4];
  const float* kb = &k[(size_t)b * Lq * Dq + h * DKq + dq * 4];
  const int* ib = &idxs[l * Uq];
  float mx = -INFINITY, sm = 0.f;
#pragma unroll
  for (int s = 0; s < Uq; ++s) {
    int j = ib[s];
    float4 kv = *(const float4*)&kb[(size_t)j * Dq];
    float p = qv.x * kv.x + qv.y * kv.y + qv.z * kv.z + qv.w * kv.w;
    p += __shfl_xor(p, 1, 64);
    p += __shfl_xor(p, 2, 64);
    p += __shfl_xor(p, 4, 64);
    p += __shfl_xor(p, 8, 64);
    mx = fmaxf(mx, p);
    sm += p;
  }
  if (dq == 0) m[slot] = mx - sm * (1.0f / Lq);
}

// ---------------------------------------------------------------------------
// top-24 per (b,h), two-stage bitonic on packed keys.
// key = (fkey(m) << 32) | (Lq-1-idx): descending sort == top_k w/ smaller-idx
// tie-break. Output set (not order) is what downstream consumes.
// ---------------------------------------------------------------------------
__device__ inline void bitonic256_desc(u64* s, int tid) {
  for (int k = 2; k <= 256; k <<= 1) {
    for (int j = k >> 1; j > 0; j >>= 1) {
      int p = tid ^ j;
      u64 mine = s[tid], other = s[p];
      u64 mx = mine > other ? mine : other;
      u64 mn = mine > other ? other : mine;
      bool dir = (tid & k) == 0;   // descending block
      bool lower = tid < p;
      u64 res = dir ? (lower ? mx : mn) : (lower ? mn : mx);
      __syncthreads();
      s[tid] = res;
      __syncthreads();
    }
  }
}

__global__ __launch_bounds__(256) void topk_stage1(
    const float* __restrict__ m, u64* __restrict__ cand) {
  __shared__ u64 s[256];
  int bh = blockIdx.x >> 3;      // 0..31
  int ch = blockIdx.x & 7;       // chunk 0..7
  int tid = threadIdx.x;
  int gidx = ch * 256 + tid;
  float v = m[(size_t)bh * Lq + gidx];
  s[tid] = ((u64)fkey(v) << 32) | (u64)(Lq - 1 - gidx);
  __syncthreads();
  bitonic256_desc(s, tid);
  if (tid < Uq) cand[((size_t)bh * TKCH + ch) * Uq + tid] = s[tid];
}

__global__ __launch_bounds__(256) void topk_stage2(
    const u64* __restrict__ cand, int* __restrict__ mtop) {
  __shared__ u64 s[256];
  int bh = blockIdx.x;
  int tid = threadIdx.x;
  s[tid] = (tid < TKCH * Uq) ? cand[(size_t)bh * TKCH * Uq + tid] : 0ull;
  __syncthreads();
  bitonic256_desc(s, tid);
  if (tid < Uq) mtop[bh * Uq + tid] = Lq - 1 - (int)(s[tid] & 0xFFFFFFFFull);
}

// repl[b,h,l] = u if l == mtop[b,h,u] else -1 (table pre-filled with -1)
__global__ void scatter_repl(const int* __restrict__ mtop, int* __restrict__ repl) {
  int t = blockIdx.x * blockDim.x + threadIdx.x;
  if (t < Bq * Hq * Uq) {
    int bh = t / Uq;
    repl[(size_t)bh * Lq + mtop[t]] = t % Uq;
  }
}

// ---------------------------------------------------------------------------
// scores[bh][u][j] = (q[b,i0[u],h,:] . k[b,j,h,:]) / sqrt(D)
// ---------------------------------------------------------------------------
#define JT 256
#define JS 64

__global__ __launch_bounds__(256) void scores_kernel(
    const float* __restrict__ q, const float* __restrict__ k,
    const int* __restrict__ mtop, float* __restrict__ scg) {
  __shared__ float qs[Uq][DKq + 1];
  __shared__ float ks[JS][DKq + 1];
  __shared__ int i0s[Uq];
  int bh = blockIdx.y;
  int jt = blockIdx.x;
  int h = bh & (Hq - 1);
  int b = bh >> 3;
  int tid = threadIdx.x;
  if (tid < Uq) i0s[tid] = mtop[bh * Uq + tid];
  __syncthreads();
  for (int s = tid; s < Uq * 16; s += 256) {
    int u = s >> 4, qd = (s & 15) * 4;
    float4 t = *(const float4*)&q[((size_t)b * Lq + i0s[u]) * Dq + h * DKq + qd];
    qs[u][qd] = t.x; qs[u][qd + 1] = t.y; qs[u][qd + 2] = t.z; qs[u][qd + 3] = t.w;
  }
  int jp = tid & 31;
  int ug = tid >> 5;
  const float scale = 0.044194173824159216f;  // 1/sqrt(512)
  for (int sub = 0; sub < JT / JS; ++sub) {
    int jbase = jt * JT + sub * JS;
    __syncthreads();
    for (int s = tid; s < JS * 16; s += 256) {
      int j = s >> 4, qd = (s & 15) * 4;
      float4 t = *(const float4*)&k[((size_t)b * Lq + jbase + j) * Dq + h * DKq + qd];
      ks[j][qd] = t.x; ks[j][qd + 1] = t.y; ks[j][qd + 2] = t.z; ks[j][qd + 3] = t.w;
    }
    __syncthreads();
    float acc[3][2] = {};
    int j0 = jp * 2, j1 = j0 + 1;
#pragma unroll 8
    for (int d = 0; d < DKq; ++d) {
      float k0 = ks[j0][d], k1 = ks[j1][d];
#pragma unroll
      for (int uu = 0; uu < 3; ++uu) {
        float qv = qs[ug * 3 + uu][d];
        acc[uu][0] += qv * k0;
        acc[uu][1] += qv * k1;
      }
    }
#pragma unroll
    for (int uu = 0; uu < 3; ++uu) {
      int u = ug * 3 + uu;
      scg[((size_t)(bh * Uq + u)) * Lq + jbase + j0] = acc[uu][0] * scale;
      scg[((size_t)(bh * Uq + u)) * Lq + jbase + j1] = acc[uu][1] * scale;
    }
  }
}

// ---------------------------------------------------------------------------
// softmax+PV, split over j-chunks of 256 for TLP.
// ---------------------------------------------------------------------------
__global__ __launch_bounds__(256) void softmax_pv_partial(
    const float* __restrict__ scg, const float* __restrict__ v,
    const int* __restrict__ mtop, float* __restrict__ pmax,
    float* __restrict__ psum, float* __restrict__ pvp) {
  int blk = blockIdx.y;  // bh*U + u
  int jc = blockIdx.x;
  int bh = blk / Uq;
  int h = bh & (Hq - 1);
  int b = bh >> 3;
  int n = mtop[blk] + 1;   // causal bound
  int j0 = jc * JCH;
  if (j0 >= n) return;
  int cnt = min(JCH, n - j0);
  int tid = threadIdx.x, wave = tid >> 6, lane = tid & 63;
  __shared__ float es[JCH];
  __shared__ float red[4][DKq];
  __shared__ float rr[4];

  const float* row = &scg[(size_t)blk * Lq + j0];
  float mx = (tid < cnt) ? row[tid] : -INFINITY;
#pragma unroll
  for (int off = 32; off; off >>= 1) mx = fmaxf(mx, __shfl_xor(mx, off, 64));
  if (lane == 0) rr[wave] = mx;
  __syncthreads();
  mx = fmaxf(fmaxf(rr[0], rr[1]), fmaxf(rr[2], rr[3]));
  __syncthreads();

  float e = (tid < cnt) ? __expf(row[tid] - mx) : 0.f;
  es[tid] = e;
  float sm = e;
#pragma unroll
  for (int off = 32; off; off >>= 1) sm += __shfl_xor(sm, off, 64);
  if (lane == 0) rr[wave] = sm;
  __syncthreads();

  float acc = 0.f;
  const float* vb = &v[((size_t)b * Lq + j0) * Dq + h * DKq + lane];
  int jlo = wave * 64;
  int jhi = min(jlo + 64, cnt);
#pragma unroll 4
  for (int j = jlo; j < jhi; ++j) acc += es[j] * vb[(size_t)j * Dq];
  red[wave][lane] = acc;
  __syncthreads();
  if (wave == 0) {
    if (lane == 0) {
      pmax[blk * NCH + jc] = mx;
      psum[blk * NCH + jc] = rr[0] + rr[1] + rr[2] + rr[3];
    }
    pvp[((size_t)blk * NCH + jc) * DKq + lane] =
        red[0][lane] + red[1][lane] + red[2][lane] + red[3][lane];
  }
}

__global__ __launch_bounds__(256) void softmax_pv_combine(
    const float* __restrict__ pmax, const float* __restrict__ psum,
    const float* __restrict__ pvp, const int* __restrict__ mtop,
    float* __restrict__ attnv) {
  int blk = blockIdx.x * 4 + (threadIdx.x >> 6);  // bh*U + u
  int lane = threadIdx.x & 63;
  int n = mtop[blk] + 1;
  int nc = (n + JCH - 1) / JCH;
  float gmax = -INFINITY;
  for (int c = 0; c < nc; ++c) gmax = fmaxf(gmax, pmax[blk * NCH + c]);
  float tot = 0.f, acc = 0.f;
  for (int c = 0; c < nc; ++c) {
    float w = __expf(pmax[blk * NCH + c] - gmax);
    tot += psum[blk * NCH + c] * w;
    acc += pvp[((size_t)blk * NCH + c) * DKq + lane] * w;
  }
  attnv[(size_t)blk * DKq + lane] = acc / tot;
}

// ---------------------------------------------------------------------------
// cumsum over L: 512-block tiled scan, float4 per thread, 16-row tiles
// ---------------------------------------------------------------------------
__global__ __launch_bounds__(128) void tile_sum(const float* __restrict__ v,
                                                float* __restrict__ tsum) {
  int blk = blockIdx.x;  // b*NTILE + tile
  int tile = blk & (NTILE - 1);
  int b = blk >> 7;
  int d4 = threadIdx.x;  // 0..127 (float4 column slice)
  float4 s = {0.f, 0.f, 0.f, 0.f};
  const float* base = &v[((size_t)b * Lq + tile * TSCAN) * Dq + d4 * 4];
#pragma unroll
  for (int r = 0; r < TSCAN; ++r) {
    float4 x = *(const float4*)&base[(size_t)r * Dq];
    s.x += x.x; s.y += x.y; s.z += x.z; s.w += x.w;
  }
  *(float4*)&tsum[((size_t)b * NTILE + tile) * Dq + d4 * 4] = s;
}

__global__ void tile_prefix(float* __restrict__ tsum) {
  int t = blockIdx.x * blockDim.x + threadIdx.x;  // B*D lanes
  if (t >= Bq * Dq) return;
  int b = t / Dq;
  int d = t % Dq;
  float run = 0.f;
  for (int i = 0; i < NTILE; ++i) {
    size_t off = ((size_t)b * NTILE + i) * Dq + d;
    float x = tsum[off];
    tsum[off] = run;
    run += x;
  }
}

__global__ __launch_bounds__(128) void build_context(
    const float* __restrict__ v, const float* __restrict__ tsum,
    const int* __restrict__ repl, const float* __restrict__ attnv,
    float* __restrict__ ctx) {
  int blk = blockIdx.x;  // b*NTILE + tile
  int tile = blk & (NTILE - 1);
  int b = blk >> 7;
  int d4 = threadIdx.x;          // float4 column slice
  int h = d4 >> 4;               // (d4*4)>>6
  float4 run = *(const float4*)&tsum[((size_t)b * NTILE + tile) * Dq + d4 * 4];
  const int* replb = &repl[(size_t)(b * Hq + h) * Lq + tile * TSCAN];
  const float* vb = &v[((size_t)b * Lq + tile * TSCAN) * Dq + d4 * 4];
  float* cb = &ctx[((size_t)b * Lq + tile * TSCAN) * Dq + d4 * 4];
  const float* ab = &attnv[(size_t)(b * Hq + h) * Uq * DKq + (d4 & 15) * 4];
#pragma unroll
  for (int r = 0; r < TSCAN; ++r) {
    float4 x = *(const float4*)&vb[(size_t)r * Dq];
    run.x += x.x; run.y += x.y; run.z += x.z; run.w += x.w;
    int u = replb[r];
    float4 val = run;
    if (u >= 0) val = *(const float4*)&ab[(size_t)u * DKq];
    *(float4*)&cb[(size_t)r * Dq] = val;
  }
}

// ---------------------------------------------------------------------------
extern "C" void kernel_launch(void* const* d_in, const int* in_sizes, int n_in,
                              void* d_out, int out_size, void* d_ws,
                              size_t ws_size, hipStream_t stream) {
  const float* queries = (const float*)d_in[0];
  const float* keys    = (const float*)d_in[1];
  const float* values  = (const float*)d_in[2];
  const int*   idxs    = (const int*)d_in[3];
  const float* Wq = (const float*)d_in[4];
  const float* bq = (const float*)d_in[5];
  const float* Wk = (const float*)d_in[6];
  const float* bk = (const float*)d_in[7];
  const float* Wv = (const float*)d_in[8];
  const float* bv = (const float*)d_in[9];
  const float* Wo = (const float*)d_in[10];
  const float* bo = (const float*)d_in[11];
  float* out = (float*)d_out;

  const size_t BLD = (size_t)Bq * Lq * Dq;  // 4,194,304
  char* w = (char*)d_ws;
  float* q    = (float*)w; w += BLD * 4;
  float* k    = (float*)w; w += BLD * 4;
  float* v    = (float*)w; w += BLD * 4;
  float* ctx  = (float*)w; w += BLD * 4;
  float* m    = (float*)w; w += (size_t)Bq * Hq * Lq * 4;
  float* attnv= (float*)w; w += (size_t)Bq * Hq * Uq * DKq * 4;
  float* tsum = (float*)w; w += (size_t)Bq * NTILE * Dq * 4;
  int* mtop   = (int*)w;   w += Bq * Hq * Uq * 4;
  int* repl   = (int*)w;   w += (size_t)Bq * Hq * Lq * 4;
  float* pmax = (float*)w; w += (size_t)Bq * Hq * Uq * NCH * 4;
  float* psum = (float*)w; w += (size_t)Bq * Hq * Uq * NCH * 4;
  float* pvp  = (float*)w; w += (size_t)Bq * Hq * Uq * NCH * DKq * 4;
  u64* cand   = (u64*)w;   w += (size_t)Bq * Hq * TKCH * Uq * 8;
  ushort_t* Ah = (ushort_t*)w; w += BLD * 2;   // reused across all 4 GEMMs
  ushort_t* Al = (ushort_t*)w; w += BLD * 2;
  const size_t WSZ = 512 * 512;
  ushort_t* Wqh = (ushort_t*)w; w += WSZ * 2;
  ushort_t* Wql = (ushort_t*)w; w += WSZ * 2;
  ushort_t* Wkh = (ushort_t*)w; w += WSZ * 2;
  ushort_t* Wkl = (ushort_t*)w; w += WSZ * 2;
  ushort_t* Wvh = (ushort_t*)w; w += WSZ * 2;
  ushort_t* Wvl = (ushort_t*)w; w += WSZ * 2;
  ushort_t* Woh = (ushort_t*)w; w += WSZ * 2;
  ushort_t* Wol = (ushort_t*)w; w += WSZ * 2;
  float* scg = ctx;  // scores alias ctx (consumed before ctx written)

  dim3 tgrid(16, 16);
  transpose_cast<<<tgrid, 256, 0, stream>>>(Wq, Wqh, Wql);
  transpose_cast<<<tgrid, 256, 0, stream>>>(Wk, Wkh, Wkl);
  transpose_cast<<<tgrid, 256, 0, stream>>>(Wv, Wvh, Wvl);
  transpose_cast<<<tgrid, 256, 0, stream>>>(Wo, Woh, Wol);

  dim3 ggrid(64, 8);  // M=8192/128, N=512/64
  const int CAST_B = (int)(BLD / 4 / 256);  // 4096 blocks

  // Q/K projections: split-bf16 (top-k-safe). V: plain bf16.
  cast_hilo<<<CAST_B, 256, 0, stream>>>(queries, Ah, Al, (int)(BLD / 4));
  gemm_split<<<ggrid, 256, 0, stream>>>(Ah, Al, Wqh, Wql, bq, q);
  cast_hilo<<<CAST_B, 256, 0, stream>>>(keys, Ah, Al, (int)(BLD / 4));
  gemm_split<<<ggrid, 256, 0, stream>>>(Ah, Al, Wkh, Wkl, bk, k);
  cast_hi<<<CAST_B, 256, 0, stream>>>(values, Ah, (int)(BLD / 4));
  gemm_bf16<<<ggrid, 256, 0, stream>>>(Ah, Wvh, bv, v);

  // sparsity metric + top-k (two-stage bitonic)
  compute_m<<<(Bq * Hq * Lq) / 16, 256, 0, stream>>>(q, k, idxs, m);
  topk_stage1<<<Bq * Hq * TKCH, 256, 0, stream>>>(m, cand);
  topk_stage2<<<Bq * Hq, 256, 0, stream>>>(cand, mtop);

  hipMemsetAsync(repl, 0xFF, (size_t)Bq * Hq * Lq * sizeof(int), stream);
  scatter_repl<<<3, 256, 0, stream>>>(mtop, repl);

  // attention on the top-24 rows
  {
    dim3 sgrid(Lq / JT, Bq * Hq);  // (8, 32)
    scores_kernel<<<sgrid, 256, 0, stream>>>(q, k, mtop, scg);
  }
  {
    dim3 pgrid(NCH, Bq * Hq * Uq);  // (8, 768)
    softmax_pv_partial<<<pgrid, 256, 0, stream>>>(scg, v, mtop, pmax, psum, pvp);
    softmax_pv_combine<<<Bq * Hq * Uq / 4, 256, 0, stream>>>(pmax, psum, pvp,
                                                             mtop, attnv);
  }

  // cumsum context + scatter (512-block scan, 16-row tiles)
  tile_sum<<<Bq * NTILE, 128, 0, stream>>>(v, tsum);
  tile_prefix<<<(Bq * Dq + 255) / 256, 256, 0, stream>>>(tsum);
  build_context<<<Bq * NTILE, 128, 0, stream>>>(v, tsum, repl, attnv, ctx);

  // output projection (plain bf16)
  cast_hi<<<CAST_B, 256, 0, stream>>>(ctx, Ah, (int)(BLD / 4));
  gemm_bf16<<<ggrid, 256, 0, stream>>>(Ah, Woh, bo, out);
}